// Round 2
// baseline (612.514 us; speedup 1.0000x reference)
//
#include <hip/hip_runtime.h>
#include <hip/hip_bf16.h>
#include <math.h>

// ---------------- graph preprocessing ----------------

__global__ void k_hist(const int* __restrict__ dst, int E, int* __restrict__ deg) {
    int e = blockIdx.x * 256 + threadIdx.x;
    if (e < E) atomicAdd(&deg[dst[e]], 1);
}

__global__ void k_scan_sum(const int* __restrict__ deg, int n, int* __restrict__ blksum) {
    __shared__ int sd[256];
    int t = threadIdx.x;
    int base = blockIdx.x * 1024 + t * 4;
    int s = 0;
    if (base + 3 < n) {
        int4 v = *(const int4*)(deg + base);
        s = v.x + v.y + v.z + v.w;
    } else {
        for (int j = 0; j < 4; ++j) if (base + j < n) s += deg[base + j];
    }
    sd[t] = s; __syncthreads();
    for (int o = 128; o > 0; o >>= 1) {
        if (t < o) sd[t] += sd[t + o];
        __syncthreads();
    }
    if (t == 0) blksum[blockIdx.x] = sd[0];
}

__global__ void k_scan_blk(int* blksum, int nb) {
    if (blockIdx.x == 0 && threadIdx.x == 0) {
        int run = 0;
        for (int i = 0; i < nb; ++i) { int v = blksum[i]; blksum[i] = run; run += v; }
    }
}

__global__ void k_scan_out(const int* __restrict__ deg, int n, const int* __restrict__ blkoff,
                           int* __restrict__ offsets, float* __restrict__ dis, int E) {
    __shared__ int sa[256];
    __shared__ int sb[256];
    int t = threadIdx.x;
    int base = blockIdx.x * 1024 + t * 4;
    int v[4]; int s = 0;
    for (int j = 0; j < 4; ++j) {
        int idx = base + j;
        v[j] = (idx < n) ? deg[idx] : 0;
        s += v[j];
    }
    int* cur = sa; int* nxt = sb;
    cur[t] = s; __syncthreads();
    for (int o = 1; o < 256; o <<= 1) {
        int val = cur[t] + ((t >= o) ? cur[t - o] : 0);
        nxt[t] = val; __syncthreads();
        int* tmp = cur; cur = nxt; nxt = tmp;
    }
    int ex = cur[t] - s;
    int run = blkoff[blockIdx.x] + ex;
    for (int j = 0; j < 4; ++j) {
        int idx = base + j;
        if (idx < n) {
            offsets[idx] = run;
            dis[idx] = rsqrtf((float)v[j] + 1.0f);
            run += v[j];
        }
    }
    if (blockIdx.x == 0 && t == 0) offsets[n] = E;
}

// ---------------- bucketed CSR build (write-amp-free) ----------------
// bucket = dst >> 6 (64 dsts per bucket); packed entry: src | ((dst&63)<<17)

__global__ void k_binit(const int* __restrict__ offsets, int nb, int N, int* __restrict__ bcursor) {
    int b = blockIdx.x * 256 + threadIdx.x;
    if (b < nb) bcursor[b] = offsets[min(b << 6, N)];
}

__global__ void k_bucket(const int* __restrict__ src, const int* __restrict__ dst, int E,
                         int* __restrict__ bcursor, int* __restrict__ pairs) {
    int e = blockIdx.x * 256 + threadIdx.x;
    if (e < E) {
        int d = dst[e];
        int p = atomicAdd(&bcursor[d >> 6], 1);
        pairs[p] = src[e] | ((d & 63) << 17);
    }
}

__global__ __launch_bounds__(256) void k_place(const int* __restrict__ offsets,
                                               const int* __restrict__ pairs,
                                               int* __restrict__ csr, int N) {
    __shared__ int cur[64];
    __shared__ int buf[2304];
    int b  = blockIdx.x;
    int d0 = b << 6;
    int dn = min(64, N - d0);
    int beg = offsets[d0];
    int end = offsets[min(d0 + 64, N)];
    int cnt = end - beg;
    int t = threadIdx.x;
    if (t < 64) cur[t] = (t < dn) ? (offsets[d0 + t] - beg) : 0;
    __syncthreads();
    if (cnt <= 2304) {
        for (int i = t; i < cnt; i += 256) {
            int v = pairs[beg + i];
            int p = atomicAdd(&cur[v >> 17], 1);
            buf[p] = v & 0x1FFFF;
        }
        __syncthreads();
        for (int i = t; i < cnt; i += 256) csr[beg + i] = buf[i];
    } else {  // overflow fallback (statistically never)
        for (int i = t; i < cnt; i += 256) {
            int v = pairs[beg + i];
            int p = atomicAdd(&cur[v >> 17], 1);
            csr[beg + p] = v & 0x1FFFF;
        }
    }
}

// ---------------- fused GEMM:  G = (A @ W) * dis[row] ----------------
// W staged in LDS (un-padded, conflict-free strided col access); A streamed
// from global (64B line reuse across 4 k-steps; wave-broadcast across cg lanes).
template<int NCOL, int THREADS>
__global__ __launch_bounds__(THREADS, 4) void k_gemm2(
    const float* __restrict__ A, const float* __restrict__ W,
    const float* __restrict__ dis, float* __restrict__ G, int M)
{
    constexpr int K  = 128;
    constexpr int CG = NCOL / 8;       // col groups: 16 (layer1) / 8 (layer2)
    constexpr int RG = THREADS / CG;   // 32
    constexpr int TM = 128 / RG;       // 4
    constexpr int BR = 128;

    __shared__ float Ws[K][NCOL];      // 64 KB (layer1) / 32 KB (layer2)

    const int tid  = threadIdx.x;
    const int row0 = blockIdx.x * BR;
    const int cg   = tid % CG;
    const int rg   = tid / CG;

    for (int f = tid; f < K * NCOL / 4; f += THREADS) {
        int k  = f / (NCOL / 4);
        int cq = f % (NCOL / 4);
        *(float4*)(&Ws[k][4 * cq]) = *(const float4*)(W + (size_t)k * NCOL + 4 * cq);
    }
    __syncthreads();

    int   rows[TM];
    const float* Ap[TM];
    #pragma unroll
    for (int i = 0; i < TM; ++i) {
        rows[i] = row0 + rg + RG * i;
        int rc = rows[i] < M ? rows[i] : (M - 1);      // clamp: no OOB reads
        Ap[i] = A + (size_t)rc * K;
    }

    float acc[TM][8];
    #pragma unroll
    for (int i = 0; i < TM; ++i)
        #pragma unroll
        for (int c = 0; c < 8; ++c) acc[i][c] = 0.f;

    for (int k0 = 0; k0 < K; k0 += 4) {
        float4 af[TM];
        #pragma unroll
        for (int i = 0; i < TM; ++i)
            af[i] = *(const float4*)(Ap[i] + k0);
        float bw[4][8];
        #pragma unroll
        for (int j = 0; j < 4; ++j)
            #pragma unroll
            for (int c = 0; c < 8; ++c)
                bw[j][c] = Ws[k0 + j][cg + CG * c];
        #pragma unroll
        for (int i = 0; i < TM; ++i)
            #pragma unroll
            for (int c = 0; c < 8; ++c) {
                acc[i][c] = fmaf(af[i].x, bw[0][c], acc[i][c]);
                acc[i][c] = fmaf(af[i].y, bw[1][c], acc[i][c]);
                acc[i][c] = fmaf(af[i].z, bw[2][c], acc[i][c]);
                acc[i][c] = fmaf(af[i].w, bw[3][c], acc[i][c]);
            }
    }

    #pragma unroll
    for (int i = 0; i < TM; ++i) {
        if (rows[i] < M) {
            float dd = dis[rows[i]];
            #pragma unroll
            for (int c = 0; c < 8; ++c)
                G[(size_t)rows[i] * NCOL + cg + CG * c] = acc[i][c] * dd;
        }
    }
}

// ---------------- aggregation layer 1 ----------------
__global__ __launch_bounds__(256) void k_agg1(
    const float* __restrict__ g1, const int* __restrict__ offsets,
    const int* __restrict__ csr_src, const float* __restrict__ dis,
    const float* __restrict__ b1, float* __restrict__ y1, int n)
{
    int wid  = (blockIdx.x * 256 + threadIdx.x) >> 6;
    int lane = threadIdx.x & 63;
    if (wid >= n) return;
    int d = wid;
    int beg = offsets[d], end = offsets[d + 1];

    float2 acc = ((const float2*)(g1 + (size_t)d * 128))[lane];
    int j = beg;
    for (; j + 4 <= end; j += 4) {
        int s0 = csr_src[j], s1 = csr_src[j + 1], s2 = csr_src[j + 2], s3 = csr_src[j + 3];
        float2 v0 = ((const float2*)(g1 + (size_t)s0 * 128))[lane];
        float2 v1 = ((const float2*)(g1 + (size_t)s1 * 128))[lane];
        float2 v2 = ((const float2*)(g1 + (size_t)s2 * 128))[lane];
        float2 v3 = ((const float2*)(g1 + (size_t)s3 * 128))[lane];
        acc.x += v0.x + v1.x + v2.x + v3.x;
        acc.y += v0.y + v1.y + v2.y + v3.y;
    }
    for (; j < end; ++j) {
        int s = csr_src[j];
        float2 v = ((const float2*)(g1 + (size_t)s * 128))[lane];
        acc.x += v.x; acc.y += v.y;
    }
    float dd = dis[d];
    float2 bb = ((const float2*)b1)[lane];
    float2 o;
    o.x = fmaxf(fmaf(dd, acc.x, bb.x), 0.f);
    o.y = fmaxf(fmaf(dd, acc.y, bb.y), 0.f);
    ((float2*)(y1 + (size_t)d * 128))[lane] = o;
}

// ---------------- aggregation layer 2 + L2 normalize ----------------
__global__ __launch_bounds__(256) void k_agg2(
    const float* __restrict__ g2, const int* __restrict__ offsets,
    const int* __restrict__ csr_src, const float* __restrict__ dis,
    const float* __restrict__ b2, float* __restrict__ out, int n)
{
    int wid  = (blockIdx.x * 256 + threadIdx.x) >> 6;
    int lane = threadIdx.x & 63;
    if (wid >= n) return;
    int d = wid;
    int beg = offsets[d], end = offsets[d + 1];

    float acc = g2[(size_t)d * 64 + lane];
    int j = beg;
    for (; j + 4 <= end; j += 4) {
        int s0 = csr_src[j], s1 = csr_src[j + 1], s2 = csr_src[j + 2], s3 = csr_src[j + 3];
        acc += g2[(size_t)s0 * 64 + lane] + g2[(size_t)s1 * 64 + lane]
             + g2[(size_t)s2 * 64 + lane] + g2[(size_t)s3 * 64 + lane];
    }
    for (; j < end; ++j)
        acc += g2[(size_t)csr_src[j] * 64 + lane];

    float val = fmaf(dis[d], acc, b2[lane]);

    float ss = val * val;
    #pragma unroll
    for (int o = 32; o >= 1; o >>= 1)
        ss += __shfl_xor(ss, o, 64);
    float norm = fmaxf(sqrtf(ss), 1e-12f);
    out[(size_t)d * 64 + lane] = val / norm;
}

// ---------------- launcher ----------------
extern "C" void kernel_launch(void* const* d_in, const int* in_sizes, int n_in,
                              void* d_out, int out_size, void* d_ws, size_t ws_size,
                              hipStream_t stream) {
    const float* x  = (const float*)d_in[0];
    const int*   ei = (const int*)d_in[1];
    const float* W1 = (const float*)d_in[2];
    const float* b1 = (const float*)d_in[3];
    const float* W2 = (const float*)d_in[4];
    const float* b2 = (const float*)d_in[5];

    const int N = in_sizes[0] / 128;   // 100000
    const int E = in_sizes[1] / 2;     // 1600000
    const int* src = ei;
    const int* dst = ei + E;
    const int NB = (N + 63) >> 6;      // buckets of 64 dsts

    char* ws = (char*)d_ws;
    size_t cur = 0;
    auto alloc = [&](size_t bytes) -> void* {
        void* p = ws + cur;
        cur += (bytes + 255) & ~(size_t)255;
        return p;
    };
    int*   deg     = (int*)  alloc((size_t)N * 4);
    int*   offsets = (int*)  alloc((size_t)(N + 1) * 4);
    int*   bcursor = (int*)  alloc((size_t)NB * 4);
    int*   blks    = (int*)  alloc(4096);
    float* dis     = (float*)alloc((size_t)N * 4);
    int*   csr     = (int*)  alloc((size_t)E * 4);
    float* g1      = (float*)alloc((size_t)N * 128 * 4);
    float* y1      = (float*)alloc((size_t)N * 128 * 4);
    int*   pairs   = (int*)y1;  // pair buffer dead before y1 is written
    float* g2      = g1;        // g1 dead after agg1
    float* out     = (float*)d_out;

    const int nb = (N + 1023) / 1024;

    hipMemsetAsync(deg, 0, (size_t)N * 4, stream);
    k_hist<<<(E + 255) / 256, 256, 0, stream>>>(dst, E, deg);
    k_scan_sum<<<nb, 256, 0, stream>>>(deg, N, blks);
    k_scan_blk<<<1, 1, 0, stream>>>(blks, nb);
    k_scan_out<<<nb, 256, 0, stream>>>(deg, N, blks, offsets, dis, E);
    k_binit<<<(NB + 255) / 256, 256, 0, stream>>>(offsets, NB, N, bcursor);
    k_bucket<<<(E + 255) / 256, 256, 0, stream>>>(src, dst, E, bcursor, pairs);
    k_place<<<NB, 256, 0, stream>>>(offsets, pairs, csr, N);

    // layer 1
    k_gemm2<128, 512><<<(N + 127) / 128, 512, 0, stream>>>(x, W1, dis, g1, N);
    k_agg1<<<(N * 64 + 255) / 256, 256, 0, stream>>>(g1, offsets, csr, dis, b1, y1, N);

    // layer 2
    k_gemm2<64, 256><<<(N + 127) / 128, 256, 0, stream>>>(y1, W2, dis, g2, N);
    k_agg2<<<(N * 64 + 255) / 256, 256, 0, stream>>>(g2, offsets, csr, dis, b2, out, N);
}

// Round 3
// 370.438 us; speedup vs baseline: 1.6535x; 1.6535x over previous
//
#include <hip/hip_runtime.h>
#include <hip/hip_bf16.h>
#include <math.h>

#define CSHIFT 9                 // 512 dsts per coarse bucket
#define TILE   8192              // edges per partition block

// ---------------- coarse histogram (per-block LDS, block-granular global atomics) ----------------
__global__ __launch_bounds__(256) void k_chist(const int* __restrict__ dst, int E,
                                               int* __restrict__ chist, int NC) {
    __shared__ int h[256];
    int t = threadIdx.x;
    h[t] = 0; __syncthreads();
    #pragma unroll 4
    for (int k = 0; k < TILE / 256; ++k) {
        int e = blockIdx.x * TILE + k * 256 + t;
        if (e < E) atomicAdd(&h[dst[e] >> CSHIFT], 1);
    }
    __syncthreads();
    if (t < NC && h[t]) atomicAdd(&chist[t], h[t]);
}

__global__ void k_cscan(const int* __restrict__ chist, int NC, int E,
                        int* __restrict__ cbase, int* __restrict__ ccursor) {
    __shared__ int sa[256], sb[256];
    int t = threadIdx.x;
    int v = (t < NC) ? chist[t] : 0;
    int* cur = sa; int* nxt = sb;
    cur[t] = v; __syncthreads();
    for (int o = 1; o < 256; o <<= 1) {
        int val = cur[t] + ((t >= o) ? cur[t - o] : 0);
        nxt[t] = val; __syncthreads();
        int* tmp = cur; cur = nxt; nxt = tmp;
    }
    int ex = cur[t] - v;
    if (t < NC) { cbase[t] = ex; ccursor[t] = ex; }
    if (t == 0) cbase[NC] = E;
}

// ---------------- partition pass: LDS-sorted tile, coalesced chunk dump ----------------
__global__ __launch_bounds__(256) void k_part(const int* __restrict__ src,
                                              const int* __restrict__ dst, int E,
                                              int* __restrict__ ccursor,
                                              int* __restrict__ pairs, int NC) {
    __shared__ int stg[TILE];
    __shared__ unsigned char sbk[TILE];
    __shared__ int h[256], lo[256], delta[256], cur[256];
    __shared__ int sa[256], sb[256];
    int t = threadIdx.x;
    int base = blockIdx.x * TILE;
    int cnt = min(TILE, E - base);

    h[t] = 0; __syncthreads();
    #pragma unroll 4
    for (int k = 0; k < TILE / 256; ++k) {
        int e = base + k * 256 + t;
        if (e < E) atomicAdd(&h[dst[e] >> CSHIFT], 1);
    }
    __syncthreads();
    int myc = h[t];
    int* c_ = sa; int* n_ = sb;
    c_[t] = myc; __syncthreads();
    for (int o = 1; o < 256; o <<= 1) {
        int val = c_[t] + ((t >= o) ? c_[t - o] : 0);
        n_[t] = val; __syncthreads();
        int* tmp = c_; c_ = n_; n_ = tmp;
    }
    int ex = c_[t] - myc;
    lo[t] = ex; cur[t] = ex;
    int g = 0;
    if (t < NC && myc) g = atomicAdd(&ccursor[t], myc);   // one chunk-reserve per (block,bucket)
    delta[t] = g - ex;
    __syncthreads();

    #pragma unroll 4
    for (int k = 0; k < TILE / 256; ++k) {
        int e = base + k * 256 + t;
        if (e < E) {
            int d = dst[e];
            int b = d >> CSHIFT;
            int p = atomicAdd(&cur[b], 1);
            stg[p] = src[e] | ((d & 511) << 17);
            sbk[p] = (unsigned char)b;
        }
    }
    __syncthreads();

    for (int i = t; i < cnt; i += 256)
        pairs[delta[sbk[i]] + i] = stg[i];
}

// ---------------- per-bucket degree (no global atomics) ----------------
__global__ __launch_bounds__(256) void k_deg(const int* __restrict__ cbase,
                                             const int* __restrict__ pairs,
                                             int* __restrict__ deg, int N) {
    __shared__ int h[512];
    int b = blockIdx.x, t = threadIdx.x;
    h[t] = 0; h[t + 256] = 0; __syncthreads();
    int beg = cbase[b], end = cbase[b + 1];
    for (int i = beg + t; i < end; i += 256) atomicAdd(&h[pairs[i] >> 17], 1);
    __syncthreads();
    int d0 = b << CSHIFT;
    for (int j = t; j < 512; j += 256) {
        int d = d0 + j;
        if (d < N) deg[d] = h[j];
    }
}

// ---------------- global exclusive scan of deg -> offsets, dis ----------------
__global__ void k_scan_sum(const int* __restrict__ deg, int n, int* __restrict__ blksum) {
    __shared__ int sd[256];
    int t = threadIdx.x;
    int base = blockIdx.x * 1024 + t * 4;
    int s = 0;
    if (base + 3 < n) {
        int4 v = *(const int4*)(deg + base);
        s = v.x + v.y + v.z + v.w;
    } else {
        for (int j = 0; j < 4; ++j) if (base + j < n) s += deg[base + j];
    }
    sd[t] = s; __syncthreads();
    for (int o = 128; o > 0; o >>= 1) {
        if (t < o) sd[t] += sd[t + o];
        __syncthreads();
    }
    if (t == 0) blksum[blockIdx.x] = sd[0];
}

__global__ void k_scan_blk(int* blksum, int nb) {
    if (blockIdx.x == 0 && threadIdx.x == 0) {
        int run = 0;
        for (int i = 0; i < nb; ++i) { int v = blksum[i]; blksum[i] = run; run += v; }
    }
}

__global__ void k_scan_out(const int* __restrict__ deg, int n, const int* __restrict__ blkoff,
                           int* __restrict__ offsets, float* __restrict__ dis, int E) {
    __shared__ int sa[256];
    __shared__ int sb[256];
    int t = threadIdx.x;
    int base = blockIdx.x * 1024 + t * 4;
    int v[4]; int s = 0;
    for (int j = 0; j < 4; ++j) {
        int idx = base + j;
        v[j] = (idx < n) ? deg[idx] : 0;
        s += v[j];
    }
    int* cur = sa; int* nxt = sb;
    cur[t] = s; __syncthreads();
    for (int o = 1; o < 256; o <<= 1) {
        int val = cur[t] + ((t >= o) ? cur[t - o] : 0);
        nxt[t] = val; __syncthreads();
        int* tmp = cur; cur = nxt; nxt = tmp;
    }
    int ex = cur[t] - s;
    int run = blkoff[blockIdx.x] + ex;
    for (int j = 0; j < 4; ++j) {
        int idx = base + j;
        if (idx < n) {
            offsets[idx] = run;
            dis[idx] = rsqrtf((float)v[j] + 1.0f);
            run += v[j];
        }
    }
    if (blockIdx.x == 0 && t == 0) offsets[n] = E;
}

// ---------------- final placement: scatter stays inside one XCD's L2 ----------------
__global__ __launch_bounds__(256) void k_place(const int* __restrict__ cbase,
                                               const int* __restrict__ offsets,
                                               const int* __restrict__ pairs,
                                               int* __restrict__ csr, int N) {
    __shared__ int cur[512];
    int b = blockIdx.x, t = threadIdx.x;
    int d0 = b << CSHIFT;
    for (int j = t; j < 512; j += 256) {
        int d = d0 + j;
        cur[j] = (d < N) ? offsets[d] : 0;
    }
    __syncthreads();
    int beg = cbase[b], end = cbase[b + 1];
    for (int i = beg + t; i < end; i += 256) {
        int pk = pairs[i];
        int p = atomicAdd(&cur[pk >> 17], 1);
        csr[p] = pk & 0x1FFFF;
    }
}

// ---------------- fused GEMM:  G = (A @ W) * dis[row] ----------------
template<int NCOL, int THREADS>
__global__ __launch_bounds__(THREADS, 4) void k_gemm2(
    const float* __restrict__ A, const float* __restrict__ W,
    const float* __restrict__ dis, float* __restrict__ G, int M)
{
    constexpr int K  = 128;
    constexpr int CG = NCOL / 8;
    constexpr int RG = THREADS / CG;
    constexpr int TM = 128 / RG;
    constexpr int BR = 128;

    __shared__ float Ws[K][NCOL];

    const int tid  = threadIdx.x;
    const int row0 = blockIdx.x * BR;
    const int cg   = tid % CG;
    const int rg   = tid / CG;

    for (int f = tid; f < K * NCOL / 4; f += THREADS) {
        int k  = f / (NCOL / 4);
        int cq = f % (NCOL / 4);
        *(float4*)(&Ws[k][4 * cq]) = *(const float4*)(W + (size_t)k * NCOL + 4 * cq);
    }
    __syncthreads();

    int   rows[TM];
    const float* Ap[TM];
    #pragma unroll
    for (int i = 0; i < TM; ++i) {
        rows[i] = row0 + rg + RG * i;
        int rc = rows[i] < M ? rows[i] : (M - 1);
        Ap[i] = A + (size_t)rc * K;
    }

    float acc[TM][8];
    #pragma unroll
    for (int i = 0; i < TM; ++i)
        #pragma unroll
        for (int c = 0; c < 8; ++c) acc[i][c] = 0.f;

    for (int k0 = 0; k0 < K; k0 += 4) {
        float4 af[TM];
        #pragma unroll
        for (int i = 0; i < TM; ++i)
            af[i] = *(const float4*)(Ap[i] + k0);
        float bw[4][8];
        #pragma unroll
        for (int j = 0; j < 4; ++j)
            #pragma unroll
            for (int c = 0; c < 8; ++c)
                bw[j][c] = Ws[k0 + j][cg + CG * c];
        #pragma unroll
        for (int i = 0; i < TM; ++i)
            #pragma unroll
            for (int c = 0; c < 8; ++c) {
                acc[i][c] = fmaf(af[i].x, bw[0][c], acc[i][c]);
                acc[i][c] = fmaf(af[i].y, bw[1][c], acc[i][c]);
                acc[i][c] = fmaf(af[i].z, bw[2][c], acc[i][c]);
                acc[i][c] = fmaf(af[i].w, bw[3][c], acc[i][c]);
            }
    }

    #pragma unroll
    for (int i = 0; i < TM; ++i) {
        if (rows[i] < M) {
            float dd = dis[rows[i]];
            #pragma unroll
            for (int c = 0; c < 8; ++c)
                G[(size_t)rows[i] * NCOL + cg + CG * c] = acc[i][c] * dd;
        }
    }
}

// ---------------- aggregation layer 1 ----------------
__global__ __launch_bounds__(256) void k_agg1(
    const float* __restrict__ g1, const int* __restrict__ offsets,
    const int* __restrict__ csr_src, const float* __restrict__ dis,
    const float* __restrict__ b1, float* __restrict__ y1, int n)
{
    int wid  = (blockIdx.x * 256 + threadIdx.x) >> 6;
    int lane = threadIdx.x & 63;
    if (wid >= n) return;
    int d = wid;
    int beg = offsets[d], end = offsets[d + 1];

    float2 acc = ((const float2*)(g1 + (size_t)d * 128))[lane];
    int j = beg;
    for (; j + 4 <= end; j += 4) {
        int s0 = csr_src[j], s1 = csr_src[j + 1], s2 = csr_src[j + 2], s3 = csr_src[j + 3];
        float2 v0 = ((const float2*)(g1 + (size_t)s0 * 128))[lane];
        float2 v1 = ((const float2*)(g1 + (size_t)s1 * 128))[lane];
        float2 v2 = ((const float2*)(g1 + (size_t)s2 * 128))[lane];
        float2 v3 = ((const float2*)(g1 + (size_t)s3 * 128))[lane];
        acc.x += v0.x + v1.x + v2.x + v3.x;
        acc.y += v0.y + v1.y + v2.y + v3.y;
    }
    for (; j < end; ++j) {
        int s = csr_src[j];
        float2 v = ((const float2*)(g1 + (size_t)s * 128))[lane];
        acc.x += v.x; acc.y += v.y;
    }
    float dd = dis[d];
    float2 bb = ((const float2*)b1)[lane];
    float2 o;
    o.x = fmaxf(fmaf(dd, acc.x, bb.x), 0.f);
    o.y = fmaxf(fmaf(dd, acc.y, bb.y), 0.f);
    ((float2*)(y1 + (size_t)d * 128))[lane] = o;
}

// ---------------- aggregation layer 2 + L2 normalize ----------------
__global__ __launch_bounds__(256) void k_agg2(
    const float* __restrict__ g2, const int* __restrict__ offsets,
    const int* __restrict__ csr_src, const float* __restrict__ dis,
    const float* __restrict__ b2, float* __restrict__ out, int n)
{
    int wid  = (blockIdx.x * 256 + threadIdx.x) >> 6;
    int lane = threadIdx.x & 63;
    if (wid >= n) return;
    int d = wid;
    int beg = offsets[d], end = offsets[d + 1];

    float acc = g2[(size_t)d * 64 + lane];
    int j = beg;
    for (; j + 4 <= end; j += 4) {
        int s0 = csr_src[j], s1 = csr_src[j + 1], s2 = csr_src[j + 2], s3 = csr_src[j + 3];
        acc += g2[(size_t)s0 * 64 + lane] + g2[(size_t)s1 * 64 + lane]
             + g2[(size_t)s2 * 64 + lane] + g2[(size_t)s3 * 64 + lane];
    }
    for (; j < end; ++j)
        acc += g2[(size_t)csr_src[j] * 64 + lane];

    float val = fmaf(dis[d], acc, b2[lane]);

    float ss = val * val;
    #pragma unroll
    for (int o = 32; o >= 1; o >>= 1)
        ss += __shfl_xor(ss, o, 64);
    float norm = fmaxf(sqrtf(ss), 1e-12f);
    out[(size_t)d * 64 + lane] = val / norm;
}

// ---------------- launcher ----------------
extern "C" void kernel_launch(void* const* d_in, const int* in_sizes, int n_in,
                              void* d_out, int out_size, void* d_ws, size_t ws_size,
                              hipStream_t stream) {
    const float* x  = (const float*)d_in[0];
    const int*   ei = (const int*)d_in[1];
    const float* W1 = (const float*)d_in[2];
    const float* b1 = (const float*)d_in[3];
    const float* W2 = (const float*)d_in[4];
    const float* b2 = (const float*)d_in[5];

    const int N = in_sizes[0] / 128;   // 100000
    const int E = in_sizes[1] / 2;     // 1600000
    const int* src = ei;
    const int* dst = ei + E;
    const int NC = (N + 511) >> CSHIFT;          // 196 coarse buckets
    const int PB = (E + TILE - 1) / TILE;        // 196 partition blocks

    char* ws = (char*)d_ws;
    size_t cur = 0;
    auto alloc = [&](size_t bytes) -> void* {
        void* p = ws + cur;
        cur += (bytes + 255) & ~(size_t)255;
        return p;
    };
    int*   deg     = (int*)  alloc((size_t)N * 4);
    int*   offsets = (int*)  alloc((size_t)(N + 1) * 4);
    int*   chist   = (int*)  alloc((size_t)NC * 4);
    int*   cbase   = (int*)  alloc((size_t)(NC + 1) * 4);
    int*   ccursor = (int*)  alloc((size_t)NC * 4);
    int*   blks    = (int*)  alloc(4096);
    float* dis     = (float*)alloc((size_t)N * 4);
    int*   csr     = (int*)  alloc((size_t)E * 4);
    float* g1      = (float*)alloc((size_t)N * 128 * 4);
    float* y1      = (float*)alloc((size_t)N * 128 * 4);
    int*   pairs   = (int*)y1;  // pair buffer dead before y1 is written
    float* g2      = g1;        // g1 dead after agg1
    float* out     = (float*)d_out;

    const int nb = (N + 1023) / 1024;

    hipMemsetAsync(chist, 0, (size_t)NC * 4, stream);
    k_chist<<<PB, 256, 0, stream>>>(dst, E, chist, NC);
    k_cscan<<<1, 256, 0, stream>>>(chist, NC, E, cbase, ccursor);
    k_part<<<PB, 256, 0, stream>>>(src, dst, E, ccursor, pairs, NC);
    k_deg<<<NC, 256, 0, stream>>>(cbase, pairs, deg, N);
    k_scan_sum<<<nb, 256, 0, stream>>>(deg, N, blks);
    k_scan_blk<<<1, 1, 0, stream>>>(blks, nb);
    k_scan_out<<<nb, 256, 0, stream>>>(deg, N, blks, offsets, dis, E);
    k_place<<<NC, 256, 0, stream>>>(cbase, offsets, pairs, csr, N);

    // layer 1
    k_gemm2<128, 512><<<(N + 127) / 128, 512, 0, stream>>>(x, W1, dis, g1, N);
    k_agg1<<<(N * 64 + 255) / 256, 256, 0, stream>>>(g1, offsets, csr, dis, b1, y1, N);

    // layer 2
    k_gemm2<64, 256><<<(N + 127) / 128, 256, 0, stream>>>(y1, W2, dis, g2, N);
    k_agg2<<<(N * 64 + 255) / 256, 256, 0, stream>>>(g2, offsets, csr, dis, b2, out, N);
}

// Round 4
// 308.266 us; speedup vs baseline: 1.9870x; 1.2017x over previous
//
#include <hip/hip_runtime.h>
#include <hip/hip_bf16.h>
#include <math.h>

#define CSHIFT 9                 // 512 dsts per coarse bucket
#define TILE   4096              // edges per partition block

// ---- bf16 helpers (RNE pack, cheap unpack) ----
__device__ __forceinline__ float bf_lo(unsigned v) { return __uint_as_float(v << 16); }
__device__ __forceinline__ float bf_hi(unsigned v) { return __uint_as_float(v & 0xffff0000u); }
__device__ __forceinline__ unsigned bf_rne(float f) {
    unsigned u = __float_as_uint(f);
    return (u + 0x7fffu + ((u >> 16) & 1u)) >> 16;
}
__device__ __forceinline__ unsigned pack_bf16(float lo, float hi) {
    return bf_rne(lo) | (bf_rne(hi) << 16);
}

// ---------------- coarse histogram ----------------
__global__ __launch_bounds__(256) void k_chist(const int* __restrict__ dst, int E,
                                               int* __restrict__ chist, int NC) {
    __shared__ int h[256];
    int t = threadIdx.x;
    h[t] = 0; __syncthreads();
    #pragma unroll 4
    for (int k = 0; k < TILE / 256; ++k) {
        int e = blockIdx.x * TILE + k * 256 + t;
        if (e < E) atomicAdd(&h[dst[e] >> CSHIFT], 1);
    }
    __syncthreads();
    if (t < NC && h[t]) atomicAdd(&chist[t], h[t]);
}

__global__ void k_cscan(const int* __restrict__ chist, int NC, int E,
                        int* __restrict__ cbase, int* __restrict__ ccursor) {
    __shared__ int sa[256], sb[256];
    int t = threadIdx.x;
    int v = (t < NC) ? chist[t] : 0;
    int* cur = sa; int* nxt = sb;
    cur[t] = v; __syncthreads();
    for (int o = 1; o < 256; o <<= 1) {
        int val = cur[t] + ((t >= o) ? cur[t - o] : 0);
        nxt[t] = val; __syncthreads();
        int* tmp = cur; cur = nxt; nxt = tmp;
    }
    int ex = cur[t] - v;
    if (t < NC) { cbase[t] = ex; ccursor[t] = ex; }
    if (t == 0) cbase[NC] = E;
}

// ---------------- partition pass ----------------
__global__ __launch_bounds__(256) void k_part(const int* __restrict__ src,
                                              const int* __restrict__ dst, int E,
                                              int* __restrict__ ccursor,
                                              int* __restrict__ pairs, int NC) {
    __shared__ int stg[TILE];
    __shared__ unsigned char sbk[TILE];
    __shared__ int h[256], delta[256], cur[256];
    __shared__ int sa[256], sb[256];
    int t = threadIdx.x;
    int base = blockIdx.x * TILE;
    int cnt = min(TILE, E - base);

    h[t] = 0; __syncthreads();
    #pragma unroll 4
    for (int k = 0; k < TILE / 256; ++k) {
        int e = base + k * 256 + t;
        if (e < E) atomicAdd(&h[dst[e] >> CSHIFT], 1);
    }
    __syncthreads();
    int myc = h[t];
    int* c_ = sa; int* n_ = sb;
    c_[t] = myc; __syncthreads();
    for (int o = 1; o < 256; o <<= 1) {
        int val = c_[t] + ((t >= o) ? c_[t - o] : 0);
        n_[t] = val; __syncthreads();
        int* tmp = c_; c_ = n_; n_ = tmp;
    }
    int ex = c_[t] - myc;
    cur[t] = ex;
    int g = 0;
    if (t < NC && myc) g = atomicAdd(&ccursor[t], myc);   // one chunk-reserve per (block,bucket)
    delta[t] = g - ex;
    __syncthreads();

    #pragma unroll 4
    for (int k = 0; k < TILE / 256; ++k) {
        int e = base + k * 256 + t;
        if (e < E) {
            int d = dst[e];
            int b = d >> CSHIFT;
            int p = atomicAdd(&cur[b], 1);
            stg[p] = src[e] | ((d & 511) << 17);
            sbk[p] = (unsigned char)b;
        }
    }
    __syncthreads();

    for (int i = t; i < cnt; i += 256)
        pairs[delta[sbk[i]] + i] = stg[i];
}

// ---------------- per-bucket degree ----------------
__global__ __launch_bounds__(256) void k_deg(const int* __restrict__ cbase,
                                             const int* __restrict__ pairs,
                                             int* __restrict__ deg, int N) {
    __shared__ int h[512];
    int b = blockIdx.x, t = threadIdx.x;
    h[t] = 0; h[t + 256] = 0; __syncthreads();
    int beg = cbase[b], end = cbase[b + 1];
    for (int i = beg + t; i < end; i += 256) atomicAdd(&h[pairs[i] >> 17], 1);
    __syncthreads();
    int d0 = b << CSHIFT;
    for (int j = t; j < 512; j += 256) {
        int d = d0 + j;
        if (d < N) deg[d] = h[j];
    }
}

// ---------------- global scan of deg -> offsets, dis ----------------
__global__ void k_scan_sum(const int* __restrict__ deg, int n, int* __restrict__ blksum) {
    __shared__ int sd[256];
    int t = threadIdx.x;
    int base = blockIdx.x * 1024 + t * 4;
    int s = 0;
    if (base + 3 < n) {
        int4 v = *(const int4*)(deg + base);
        s = v.x + v.y + v.z + v.w;
    } else {
        for (int j = 0; j < 4; ++j) if (base + j < n) s += deg[base + j];
    }
    sd[t] = s; __syncthreads();
    for (int o = 128; o > 0; o >>= 1) {
        if (t < o) sd[t] += sd[t + o];
        __syncthreads();
    }
    if (t == 0) blksum[blockIdx.x] = sd[0];
}

__global__ void k_scan_blk(int* blksum, int nb) {
    if (blockIdx.x == 0 && threadIdx.x == 0) {
        int run = 0;
        for (int i = 0; i < nb; ++i) { int v = blksum[i]; blksum[i] = run; run += v; }
    }
}

__global__ void k_scan_out(const int* __restrict__ deg, int n, const int* __restrict__ blkoff,
                           int* __restrict__ offsets, float* __restrict__ dis, int E) {
    __shared__ int sa[256];
    __shared__ int sb[256];
    int t = threadIdx.x;
    int base = blockIdx.x * 1024 + t * 4;
    int v[4]; int s = 0;
    for (int j = 0; j < 4; ++j) {
        int idx = base + j;
        v[j] = (idx < n) ? deg[idx] : 0;
        s += v[j];
    }
    int* cur = sa; int* nxt = sb;
    cur[t] = s; __syncthreads();
    for (int o = 1; o < 256; o <<= 1) {
        int val = cur[t] + ((t >= o) ? cur[t - o] : 0);
        nxt[t] = val; __syncthreads();
        int* tmp = cur; cur = nxt; nxt = tmp;
    }
    int ex = cur[t] - s;
    int run = blkoff[blockIdx.x] + ex;
    for (int j = 0; j < 4; ++j) {
        int idx = base + j;
        if (idx < n) {
            offsets[idx] = run;
            dis[idx] = rsqrtf((float)v[j] + 1.0f);
            run += v[j];
        }
    }
    if (blockIdx.x == 0 && t == 0) offsets[n] = E;
}

// ---------------- final placement ----------------
__global__ __launch_bounds__(256) void k_place(const int* __restrict__ cbase,
                                               const int* __restrict__ offsets,
                                               const int* __restrict__ pairs,
                                               int* __restrict__ csr, int N) {
    __shared__ int cur[512];
    int b = blockIdx.x, t = threadIdx.x;
    int d0 = b << CSHIFT;
    for (int j = t; j < 512; j += 256) {
        int d = d0 + j;
        cur[j] = (d < N) ? offsets[d] : 0;
    }
    __syncthreads();
    int beg = cbase[b], end = cbase[b + 1];
    for (int i = beg + t; i < end; i += 256) {
        int pk = pairs[i];
        int p = atomicAdd(&cur[pk >> 17], 1);
        csr[p] = pk & 0x1FFFF;
    }
}

// ---------------- fused GEMM: G(bf16) = (A @ W) * dis[row] ----------------
// Paired-column ownership: thread owns dword-cols cg + CG*cc (cc=0..3), i.e.
// feature pairs -> 4B/lane packed bf16 stores, coalesced. LDS B-reads are
// float2, conflict-free (16 lanes span 32 banks; row-groups broadcast).
template<int NCOL, int THREADS, bool ABF16>
__global__ __launch_bounds__(THREADS, 4) void k_gemm3(
    const unsigned char* __restrict__ Ab, const float* __restrict__ W,
    const float* __restrict__ dis, unsigned* __restrict__ G, int M)
{
    constexpr int K  = 128;
    constexpr int ND = NCOL / 2;        // dword cols: 64 / 32
    constexpr int CG = ND / 4;          // 16 / 8
    constexpr int RG = THREADS / CG;    // 32
    constexpr int TM = 128 / RG;        // 4
    constexpr int BR = 128;
    constexpr size_t ASTR = ABF16 ? (size_t)K * 2 : (size_t)K * 4;

    __shared__ float Ws[K][NCOL];

    const int tid  = threadIdx.x;
    const int row0 = blockIdx.x * BR;
    const int cg   = tid % CG;
    const int rg   = tid / CG;

    for (int f = tid; f < K * NCOL / 4; f += THREADS) {
        int k  = f / (NCOL / 4);
        int cq = f % (NCOL / 4);
        *(float4*)(&Ws[k][4 * cq]) = *(const float4*)(W + (size_t)k * NCOL + 4 * cq);
    }
    __syncthreads();

    int rows[TM];
    const unsigned char* Ap[TM];
    #pragma unroll
    for (int i = 0; i < TM; ++i) {
        rows[i] = row0 + rg + RG * i;
        int rc = rows[i] < M ? rows[i] : (M - 1);
        Ap[i] = Ab + (size_t)rc * ASTR;
    }

    float acc[TM][8];
    #pragma unroll
    for (int i = 0; i < TM; ++i)
        #pragma unroll
        for (int c = 0; c < 8; ++c) acc[i][c] = 0.f;

    for (int k0 = 0; k0 < K; k0 += 4) {
        float4 af[TM];
        #pragma unroll
        for (int i = 0; i < TM; ++i) {
            if constexpr (ABF16) {
                uint2 u = *(const uint2*)(Ap[i] + (size_t)k0 * 2);
                af[i].x = bf_lo(u.x); af[i].y = bf_hi(u.x);
                af[i].z = bf_lo(u.y); af[i].w = bf_hi(u.y);
            } else {
                af[i] = *(const float4*)(Ap[i] + (size_t)k0 * 4);
            }
        }
        float2 bw[4][4];
        #pragma unroll
        for (int j = 0; j < 4; ++j)
            #pragma unroll
            for (int cc = 0; cc < 4; ++cc)
                bw[j][cc] = *(const float2*)(&Ws[k0 + j][2 * (cg + CG * cc)]);
        #pragma unroll
        for (int i = 0; i < TM; ++i)
            #pragma unroll
            for (int cc = 0; cc < 4; ++cc) {
                acc[i][2*cc]   = fmaf(af[i].x, bw[0][cc].x, acc[i][2*cc]);
                acc[i][2*cc+1] = fmaf(af[i].x, bw[0][cc].y, acc[i][2*cc+1]);
                acc[i][2*cc]   = fmaf(af[i].y, bw[1][cc].x, acc[i][2*cc]);
                acc[i][2*cc+1] = fmaf(af[i].y, bw[1][cc].y, acc[i][2*cc+1]);
                acc[i][2*cc]   = fmaf(af[i].z, bw[2][cc].x, acc[i][2*cc]);
                acc[i][2*cc+1] = fmaf(af[i].z, bw[2][cc].y, acc[i][2*cc+1]);
                acc[i][2*cc]   = fmaf(af[i].w, bw[3][cc].x, acc[i][2*cc]);
                acc[i][2*cc+1] = fmaf(af[i].w, bw[3][cc].y, acc[i][2*cc+1]);
            }
    }

    #pragma unroll
    for (int i = 0; i < TM; ++i) {
        if (rows[i] < M) {
            float dd = dis[rows[i]];
            unsigned* gr = G + (size_t)rows[i] * ND;
            #pragma unroll
            for (int cc = 0; cc < 4; ++cc)
                gr[cg + CG * cc] = pack_bf16(acc[i][2*cc] * dd, acc[i][2*cc+1] * dd);
        }
    }
}

// ---------------- aggregation layer 1 (bf16 gather, fp32 accum) ----------------
__global__ __launch_bounds__(256) void k_agg1(
    const unsigned* __restrict__ g1, const int* __restrict__ offsets,
    const int* __restrict__ csr_src, const float* __restrict__ dis,
    const float* __restrict__ b1, unsigned* __restrict__ y1, int n)
{
    int wid  = (blockIdx.x * 256 + threadIdx.x) >> 6;
    int lane = threadIdx.x & 63;
    if (wid >= n) return;
    int d = wid;
    int beg = offsets[d], end = offsets[d + 1];

    unsigned sv = g1[(size_t)d * 64 + lane];
    float ax = bf_lo(sv), ay = bf_hi(sv);
    int j = beg;
    for (; j + 4 <= end; j += 4) {
        int s0 = csr_src[j], s1 = csr_src[j + 1], s2 = csr_src[j + 2], s3 = csr_src[j + 3];
        unsigned v0 = g1[(size_t)s0 * 64 + lane];
        unsigned v1 = g1[(size_t)s1 * 64 + lane];
        unsigned v2 = g1[(size_t)s2 * 64 + lane];
        unsigned v3 = g1[(size_t)s3 * 64 + lane];
        ax += bf_lo(v0) + bf_lo(v1) + bf_lo(v2) + bf_lo(v3);
        ay += bf_hi(v0) + bf_hi(v1) + bf_hi(v2) + bf_hi(v3);
    }
    for (; j < end; ++j) {
        unsigned v = g1[(size_t)csr_src[j] * 64 + lane];
        ax += bf_lo(v); ay += bf_hi(v);
    }
    float dd = dis[d];
    float2 bb = ((const float2*)b1)[lane];
    float ox = fmaxf(fmaf(dd, ax, bb.x), 0.f);
    float oy = fmaxf(fmaf(dd, ay, bb.y), 0.f);
    y1[(size_t)d * 64 + lane] = pack_bf16(ox, oy);
}

// ---------------- aggregation layer 2 + L2 normalize ----------------
__global__ __launch_bounds__(256) void k_agg2(
    const unsigned short* __restrict__ g2, const int* __restrict__ offsets,
    const int* __restrict__ csr_src, const float* __restrict__ dis,
    const float* __restrict__ b2, float* __restrict__ out, int n)
{
    int wid  = (blockIdx.x * 256 + threadIdx.x) >> 6;
    int lane = threadIdx.x & 63;
    if (wid >= n) return;
    int d = wid;
    int beg = offsets[d], end = offsets[d + 1];

    float acc = __uint_as_float(((unsigned)g2[(size_t)d * 64 + lane]) << 16);
    int j = beg;
    for (; j + 4 <= end; j += 4) {
        int s0 = csr_src[j], s1 = csr_src[j + 1], s2 = csr_src[j + 2], s3 = csr_src[j + 3];
        acc += __uint_as_float(((unsigned)g2[(size_t)s0 * 64 + lane]) << 16)
             + __uint_as_float(((unsigned)g2[(size_t)s1 * 64 + lane]) << 16)
             + __uint_as_float(((unsigned)g2[(size_t)s2 * 64 + lane]) << 16)
             + __uint_as_float(((unsigned)g2[(size_t)s3 * 64 + lane]) << 16);
    }
    for (; j < end; ++j)
        acc += __uint_as_float(((unsigned)g2[(size_t)csr_src[j] * 64 + lane]) << 16);

    float val = fmaf(dis[d], acc, b2[lane]);

    float ss = val * val;
    #pragma unroll
    for (int o = 32; o >= 1; o >>= 1)
        ss += __shfl_xor(ss, o, 64);
    float norm = fmaxf(sqrtf(ss), 1e-12f);
    out[(size_t)d * 64 + lane] = val / norm;
}

// ---------------- launcher ----------------
extern "C" void kernel_launch(void* const* d_in, const int* in_sizes, int n_in,
                              void* d_out, int out_size, void* d_ws, size_t ws_size,
                              hipStream_t stream) {
    const float* x  = (const float*)d_in[0];
    const int*   ei = (const int*)d_in[1];
    const float* W1 = (const float*)d_in[2];
    const float* b1 = (const float*)d_in[3];
    const float* W2 = (const float*)d_in[4];
    const float* b2 = (const float*)d_in[5];

    const int N = in_sizes[0] / 128;   // 100000
    const int E = in_sizes[1] / 2;     // 1600000
    const int* src = ei;
    const int* dst = ei + E;
    const int NC = (N + 511) >> CSHIFT;          // 196 coarse buckets
    const int PB = (E + TILE - 1) / TILE;        // 391 partition blocks

    char* ws = (char*)d_ws;
    size_t cur = 0;
    auto alloc = [&](size_t bytes) -> void* {
        void* p = ws + cur;
        cur += (bytes + 255) & ~(size_t)255;
        return p;
    };
    int*      deg     = (int*)     alloc((size_t)N * 4);
    int*      offsets = (int*)     alloc((size_t)(N + 1) * 4);
    int*      chist   = (int*)     alloc((size_t)NC * 4);
    int*      cbase   = (int*)     alloc((size_t)(NC + 1) * 4);
    int*      ccursor = (int*)     alloc((size_t)NC * 4);
    int*      blks    = (int*)     alloc(4096);
    float*    dis     = (float*)   alloc((size_t)N * 4);
    int*      csr     = (int*)     alloc((size_t)E * 4);
    unsigned* g1      = (unsigned*)alloc((size_t)N * 64 * 4);  // bf16x2, 64 dwords/row
    unsigned* y1      = (unsigned*)alloc((size_t)N * 64 * 4);  // bf16x2
    int*      pairs   = (int*)y1;            // dead before y1 written
    unsigned* g2      = g1;                  // g1 dead after agg1; 32 dwords/row
    float*    out     = (float*)d_out;

    const int nb = (N + 1023) / 1024;

    hipMemsetAsync(chist, 0, (size_t)NC * 4, stream);
    k_chist<<<PB, 256, 0, stream>>>(dst, E, chist, NC);
    k_cscan<<<1, 256, 0, stream>>>(chist, NC, E, cbase, ccursor);
    k_part<<<PB, 256, 0, stream>>>(src, dst, E, ccursor, pairs, NC);
    k_deg<<<NC, 256, 0, stream>>>(cbase, pairs, deg, N);
    k_scan_sum<<<nb, 256, 0, stream>>>(deg, N, blks);
    k_scan_blk<<<1, 1, 0, stream>>>(blks, nb);
    k_scan_out<<<nb, 256, 0, stream>>>(deg, N, blks, offsets, dis, E);
    k_place<<<NC, 256, 0, stream>>>(cbase, offsets, pairs, csr, N);

    // layer 1: g1 = bf16((x @ W1) * dis)
    k_gemm3<128, 512, false><<<(N + 127) / 128, 512, 0, stream>>>(
        (const unsigned char*)x, W1, dis, g1, N);
    k_agg1<<<(N * 64 + 255) / 256, 256, 0, stream>>>(g1, offsets, csr, dis, b1, y1, N);

    // layer 2: g2 = bf16((y1 @ W2) * dis)
    k_gemm3<64, 256, true><<<(N + 127) / 128, 256, 0, stream>>>(
        (const unsigned char*)y1, W2, dis, g2, N);
    k_agg2<<<(N * 64 + 255) / 256, 256, 0, stream>>>(
        (const unsigned short*)g2, offsets, csr, dis, b2, out, N);
}

// Round 5
// 296.173 us; speedup vs baseline: 2.0681x; 1.0408x over previous
//
#include <hip/hip_runtime.h>
#include <hip/hip_bf16.h>
#include <math.h>

#define CSHIFT 9                 // 512 dsts per coarse bucket
#define TILE   4096              // edges per partition block
#define PSH    14                // padded bucket capacity = 16384 (mean fill 8163)
#define PCAP   (1 << PSH)

// ---- bf16 helpers (RNE pack, cheap unpack) ----
__device__ __forceinline__ float bf_lo(unsigned v) { return __uint_as_float(v << 16); }
__device__ __forceinline__ float bf_hi(unsigned v) { return __uint_as_float(v & 0xffff0000u); }
__device__ __forceinline__ unsigned bf_rne(float f) {
    unsigned u = __float_as_uint(f);
    return (u + 0x7fffu + ((u >> 16) & 1u)) >> 16;
}
__device__ __forceinline__ unsigned pack_bf16(float lo, float hi) {
    return bf_rne(lo) | (bf_rne(hi) << 16);
}

// ---------------- bucket cursor init (padded regions; no global histogram needed) ----------------
__global__ void k_binit(int* __restrict__ ccursor, int NC) {
    int b = blockIdx.x * 256 + threadIdx.x;
    if (b < NC) ccursor[b] = b << PSH;
}

// ---------------- partition pass: LDS hist + chunk reserve + direct scatter ----------------
__global__ __launch_bounds__(256) void k_part(const int* __restrict__ src,
                                              const int* __restrict__ dst, int E,
                                              int* __restrict__ ccursor,
                                              int* __restrict__ pairs, int NC) {
    __shared__ int sdst[TILE];
    __shared__ int h[256], delta[256], cur[256];
    int t = threadIdx.x;
    int base = blockIdx.x * TILE;

    h[t] = 0; __syncthreads();
    #pragma unroll
    for (int k = 0; k < TILE / 256; ++k) {
        int e = base + k * 256 + t;
        int d = (e < E) ? dst[e] : -1;
        sdst[k * 256 + t] = d;
        if (d >= 0) atomicAdd(&h[d >> CSHIFT], 1);
    }
    __syncthreads();
    int myc = h[t];
    int g = 0;
    if (t < NC && myc) g = atomicAdd(&ccursor[t], myc);   // one reserve per (block,bucket)
    delta[t] = g; cur[t] = 0;
    __syncthreads();

    #pragma unroll
    for (int k = 0; k < TILE / 256; ++k) {
        int e = base + k * 256 + t;
        if (e < E) {
            int d = sdst[k * 256 + t];
            int b = d >> CSHIFT;
            int p = atomicAdd(&cur[b], 1);
            pairs[delta[b] + p] = src[e] | ((d & 511) << 17);
        }
    }
}

// ---------------- per-bucket degree ----------------
__global__ __launch_bounds__(256) void k_deg(const int* __restrict__ ccursor,
                                             const int* __restrict__ pairs,
                                             int* __restrict__ deg, int N) {
    __shared__ int h[512];
    int b = blockIdx.x, t = threadIdx.x;
    h[t] = 0; h[t + 256] = 0; __syncthreads();
    int beg = b << PSH, end = ccursor[b];
    for (int i = beg + t; i < end; i += 256) atomicAdd(&h[pairs[i] >> 17], 1);
    __syncthreads();
    int d0 = b << CSHIFT;
    for (int j = t; j < 512; j += 256) {
        int d = d0 + j;
        if (d < N) deg[d] = h[j];
    }
}

// ---------------- global scan of deg -> offsets, dis ----------------
__global__ void k_scan_sum(const int* __restrict__ deg, int n, int* __restrict__ blksum) {
    __shared__ int sd[256];
    int t = threadIdx.x;
    int base = blockIdx.x * 1024 + t * 4;
    int s = 0;
    if (base + 3 < n) {
        int4 v = *(const int4*)(deg + base);
        s = v.x + v.y + v.z + v.w;
    } else {
        for (int j = 0; j < 4; ++j) if (base + j < n) s += deg[base + j];
    }
    sd[t] = s; __syncthreads();
    for (int o = 128; o > 0; o >>= 1) {
        if (t < o) sd[t] += sd[t + o];
        __syncthreads();
    }
    if (t == 0) blksum[blockIdx.x] = sd[0];
}

__global__ void k_scan_blk(int* blksum, int nb) {
    if (blockIdx.x == 0 && threadIdx.x == 0) {
        int run = 0;
        for (int i = 0; i < nb; ++i) { int v = blksum[i]; blksum[i] = run; run += v; }
    }
}

__global__ void k_scan_out(const int* __restrict__ deg, int n, const int* __restrict__ blkoff,
                           int* __restrict__ offsets, float* __restrict__ dis, int E) {
    __shared__ int sa[256];
    __shared__ int sb[256];
    int t = threadIdx.x;
    int base = blockIdx.x * 1024 + t * 4;
    int v[4]; int s = 0;
    for (int j = 0; j < 4; ++j) {
        int idx = base + j;
        v[j] = (idx < n) ? deg[idx] : 0;
        s += v[j];
    }
    int* cur = sa; int* nxt = sb;
    cur[t] = s; __syncthreads();
    for (int o = 1; o < 256; o <<= 1) {
        int val = cur[t] + ((t >= o) ? cur[t - o] : 0);
        nxt[t] = val; __syncthreads();
        int* tmp = cur; cur = nxt; nxt = tmp;
    }
    int ex = cur[t] - s;
    int run = blkoff[blockIdx.x] + ex;
    for (int j = 0; j < 4; ++j) {
        int idx = base + j;
        if (idx < n) {
            offsets[idx] = run;
            dis[idx] = rsqrtf((float)v[j] + 1.0f);
            run += v[j];
        }
    }
    if (blockIdx.x == 0 && t == 0) offsets[n] = E;
}

// ---------------- final placement: scatter stays inside one XCD's L2 ----------------
__global__ __launch_bounds__(256) void k_place(const int* __restrict__ ccursor,
                                               const int* __restrict__ offsets,
                                               const int* __restrict__ pairs,
                                               int* __restrict__ csr, int N) {
    __shared__ int cur[512];
    int b = blockIdx.x, t = threadIdx.x;
    int d0 = b << CSHIFT;
    for (int j = t; j < 512; j += 256) {
        int d = d0 + j;
        cur[j] = (d < N) ? offsets[d] : 0;
    }
    __syncthreads();
    int beg = b << PSH, end = ccursor[b];
    for (int i = beg + t; i < end; i += 256) {
        int pk = pairs[i];
        int p = atomicAdd(&cur[pk >> 17], 1);
        csr[p] = pk & 0x1FFFF;
    }
}

// ---------------- fused GEMM: G(bf16) = (A @ W) * dis[row] ----------------
template<int NCOL, int THREADS, bool ABF16>
__global__ __launch_bounds__(THREADS, 4) void k_gemm3(
    const unsigned char* __restrict__ Ab, const float* __restrict__ W,
    const float* __restrict__ dis, unsigned* __restrict__ G, int M)
{
    constexpr int K  = 128;
    constexpr int ND = NCOL / 2;        // dword cols: 64 / 32
    constexpr int CG = ND / 4;          // 16 / 8
    constexpr int RG = THREADS / CG;    // 32
    constexpr int TM = 128 / RG;        // 4
    constexpr int BR = 128;
    constexpr size_t ASTR = ABF16 ? (size_t)K * 2 : (size_t)K * 4;

    __shared__ float Ws[K][NCOL];

    const int tid  = threadIdx.x;
    const int row0 = blockIdx.x * BR;
    const int cg   = tid % CG;
    const int rg   = tid / CG;

    for (int f = tid; f < K * NCOL / 4; f += THREADS) {
        int k  = f / (NCOL / 4);
        int cq = f % (NCOL / 4);
        *(float4*)(&Ws[k][4 * cq]) = *(const float4*)(W + (size_t)k * NCOL + 4 * cq);
    }
    __syncthreads();

    int rows[TM];
    const unsigned char* Ap[TM];
    #pragma unroll
    for (int i = 0; i < TM; ++i) {
        rows[i] = row0 + rg + RG * i;
        int rc = rows[i] < M ? rows[i] : (M - 1);
        Ap[i] = Ab + (size_t)rc * ASTR;
    }

    float acc[TM][8];
    #pragma unroll
    for (int i = 0; i < TM; ++i)
        #pragma unroll
        for (int c = 0; c < 8; ++c) acc[i][c] = 0.f;

    for (int k0 = 0; k0 < K; k0 += 4) {
        float4 af[TM];
        #pragma unroll
        for (int i = 0; i < TM; ++i) {
            if constexpr (ABF16) {
                uint2 u = *(const uint2*)(Ap[i] + (size_t)k0 * 2);
                af[i].x = bf_lo(u.x); af[i].y = bf_hi(u.x);
                af[i].z = bf_lo(u.y); af[i].w = bf_hi(u.y);
            } else {
                af[i] = *(const float4*)(Ap[i] + (size_t)k0 * 4);
            }
        }
        float2 bw[4][4];
        #pragma unroll
        for (int j = 0; j < 4; ++j)
            #pragma unroll
            for (int cc = 0; cc < 4; ++cc)
                bw[j][cc] = *(const float2*)(&Ws[k0 + j][2 * (cg + CG * cc)]);
        #pragma unroll
        for (int i = 0; i < TM; ++i)
            #pragma unroll
            for (int cc = 0; cc < 4; ++cc) {
                acc[i][2*cc]   = fmaf(af[i].x, bw[0][cc].x, acc[i][2*cc]);
                acc[i][2*cc+1] = fmaf(af[i].x, bw[0][cc].y, acc[i][2*cc+1]);
                acc[i][2*cc]   = fmaf(af[i].y, bw[1][cc].x, acc[i][2*cc]);
                acc[i][2*cc+1] = fmaf(af[i].y, bw[1][cc].y, acc[i][2*cc+1]);
                acc[i][2*cc]   = fmaf(af[i].z, bw[2][cc].x, acc[i][2*cc]);
                acc[i][2*cc+1] = fmaf(af[i].z, bw[2][cc].y, acc[i][2*cc+1]);
                acc[i][2*cc]   = fmaf(af[i].w, bw[3][cc].x, acc[i][2*cc]);
                acc[i][2*cc+1] = fmaf(af[i].w, bw[3][cc].y, acc[i][2*cc+1]);
            }
    }

    #pragma unroll
    for (int i = 0; i < TM; ++i) {
        if (rows[i] < M) {
            float dd = dis[rows[i]];
            unsigned* gr = G + (size_t)rows[i] * ND;
            #pragma unroll
            for (int cc = 0; cc < 4; ++cc)
                gr[cg + CG * cc] = pack_bf16(acc[i][2*cc] * dd, acc[i][2*cc+1] * dd);
        }
    }
}

// ---------------- aggregation layer 1: half-wave per edge (2 rows / wave-load) ----------------
__global__ __launch_bounds__(256) void k_agg1(
    const unsigned* __restrict__ g1, const int* __restrict__ offsets,
    const int* __restrict__ csr_src, const float* __restrict__ dis,
    const float* __restrict__ b1, unsigned* __restrict__ y1, int n)
{
    int wid  = (blockIdx.x * 256 + threadIdx.x) >> 6;
    int lane = threadIdx.x & 63;
    if (wid >= n) return;
    int d  = wid;
    int ll = lane & 31;       // dword-pair index within row
    int hl = lane >> 5;       // which edge of the pair
    int beg = offsets[d], end = offsets[d + 1];

    float a0 = 0.f, a1 = 0.f, a2 = 0.f, a3 = 0.f;
    int j = beg;
    for (; j + 4 <= end; j += 4) {
        int sA = csr_src[j + hl];
        int sB = csr_src[j + 2 + hl];
        uint2 vA = *((const uint2*)(g1 + (size_t)sA * 64) + ll);
        uint2 vB = *((const uint2*)(g1 + (size_t)sB * 64) + ll);
        a0 += bf_lo(vA.x) + bf_lo(vB.x);
        a1 += bf_hi(vA.x) + bf_hi(vB.x);
        a2 += bf_lo(vA.y) + bf_lo(vB.y);
        a3 += bf_hi(vA.y) + bf_hi(vB.y);
    }
    for (; j < end; j += 2) {
        if (j + hl < end) {
            int s = csr_src[j + hl];
            uint2 v = *((const uint2*)(g1 + (size_t)s * 64) + ll);
            a0 += bf_lo(v.x); a1 += bf_hi(v.x);
            a2 += bf_lo(v.y); a3 += bf_hi(v.y);
        }
    }
    // combine the two half-wave partials
    a0 += __shfl_xor(a0, 32, 64);
    a1 += __shfl_xor(a1, 32, 64);
    a2 += __shfl_xor(a2, 32, 64);
    a3 += __shfl_xor(a3, 32, 64);
    // self term
    uint2 sv = *((const uint2*)(g1 + (size_t)d * 64) + ll);
    a0 += bf_lo(sv.x); a1 += bf_hi(sv.x);
    a2 += bf_lo(sv.y); a3 += bf_hi(sv.y);

    float dd = dis[d];
    float4 bb = *(const float4*)(b1 + 4 * ll);
    float o0 = fmaxf(fmaf(dd, a0, bb.x), 0.f);
    float o1 = fmaxf(fmaf(dd, a1, bb.y), 0.f);
    float o2 = fmaxf(fmaf(dd, a2, bb.z), 0.f);
    float o3 = fmaxf(fmaf(dd, a3, bb.w), 0.f);
    if (lane < 32) {
        uint2 w;
        w.x = pack_bf16(o0, o1);
        w.y = pack_bf16(o2, o3);
        *((uint2*)(y1 + (size_t)d * 64) + ll) = w;
    }
}

// ---------------- aggregation layer 2 + L2 normalize: quarter-wave per edge ----------------
__global__ __launch_bounds__(256) void k_agg2(
    const unsigned* __restrict__ g2, const int* __restrict__ offsets,
    const int* __restrict__ csr_src, const float* __restrict__ dis,
    const float* __restrict__ b2, float* __restrict__ out, int n)
{
    int wid  = (blockIdx.x * 256 + threadIdx.x) >> 6;
    int lane = threadIdx.x & 63;
    if (wid >= n) return;
    int d  = wid;
    int ql = lane & 15;       // dword-pair index within row (row = 32 dwords)
    int qh = lane >> 4;       // which edge of the quad (0..3)
    int beg = offsets[d], end = offsets[d + 1];

    float a0 = 0.f, a1 = 0.f, a2 = 0.f, a3 = 0.f;
    int j = beg;
    for (; j + 8 <= end; j += 8) {
        int sA = csr_src[j + qh];
        int sB = csr_src[j + 4 + qh];
        uint2 vA = *((const uint2*)(g2 + (size_t)sA * 32) + ql);
        uint2 vB = *((const uint2*)(g2 + (size_t)sB * 32) + ql);
        a0 += bf_lo(vA.x) + bf_lo(vB.x);
        a1 += bf_hi(vA.x) + bf_hi(vB.x);
        a2 += bf_lo(vA.y) + bf_lo(vB.y);
        a3 += bf_hi(vA.y) + bf_hi(vB.y);
    }
    for (; j < end; j += 4) {
        if (j + qh < end) {
            int s = csr_src[j + qh];
            uint2 v = *((const uint2*)(g2 + (size_t)s * 32) + ql);
            a0 += bf_lo(v.x); a1 += bf_hi(v.x);
            a2 += bf_lo(v.y); a3 += bf_hi(v.y);
        }
    }
    // combine the four quarter-wave partials
    a0 += __shfl_xor(a0, 16, 64); a0 += __shfl_xor(a0, 32, 64);
    a1 += __shfl_xor(a1, 16, 64); a1 += __shfl_xor(a1, 32, 64);
    a2 += __shfl_xor(a2, 16, 64); a2 += __shfl_xor(a2, 32, 64);
    a3 += __shfl_xor(a3, 16, 64); a3 += __shfl_xor(a3, 32, 64);
    // self term
    uint2 sv = *((const uint2*)(g2 + (size_t)d * 32) + ql);
    a0 += bf_lo(sv.x); a1 += bf_hi(sv.x);
    a2 += bf_lo(sv.y); a3 += bf_hi(sv.y);

    float dd = dis[d];
    float4 bb = *(const float4*)(b2 + 4 * ql);
    float v0 = fmaf(dd, a0, bb.x);
    float v1 = fmaf(dd, a1, bb.y);
    float v2 = fmaf(dd, a2, bb.z);
    float v3 = fmaf(dd, a3, bb.w);

    float ss = v0 * v0 + v1 * v1 + v2 * v2 + v3 * v3;
    #pragma unroll
    for (int o = 8; o >= 1; o >>= 1)
        ss += __shfl_xor(ss, o, 64);
    float inv = 1.0f / fmaxf(sqrtf(ss), 1e-12f);
    if (lane < 16) {
        float4 w = make_float4(v0 * inv, v1 * inv, v2 * inv, v3 * inv);
        *((float4*)(out + (size_t)d * 64) + ql) = w;
    }
}

// ---------------- launcher ----------------
extern "C" void kernel_launch(void* const* d_in, const int* in_sizes, int n_in,
                              void* d_out, int out_size, void* d_ws, size_t ws_size,
                              hipStream_t stream) {
    const float* x  = (const float*)d_in[0];
    const int*   ei = (const int*)d_in[1];
    const float* W1 = (const float*)d_in[2];
    const float* b1 = (const float*)d_in[3];
    const float* W2 = (const float*)d_in[4];
    const float* b2 = (const float*)d_in[5];

    const int N = in_sizes[0] / 128;   // 100000
    const int E = in_sizes[1] / 2;     // 1600000
    const int* src = ei;
    const int* dst = ei + E;
    const int NC = (N + 511) >> CSHIFT;          // 196 coarse buckets
    const int PB = (E + TILE - 1) / TILE;        // 391 partition blocks

    char* ws = (char*)d_ws;
    size_t cur = 0;
    auto alloc = [&](size_t bytes) -> void* {
        void* p = ws + cur;
        cur += (bytes + 255) & ~(size_t)255;
        return p;
    };
    int*      deg     = (int*)     alloc((size_t)N * 4);
    int*      offsets = (int*)     alloc((size_t)(N + 1) * 4);
    int*      ccursor = (int*)     alloc((size_t)NC * 4);
    int*      blks    = (int*)     alloc(4096);
    float*    dis     = (float*)   alloc((size_t)N * 4);
    int*      csr     = (int*)     alloc((size_t)E * 4);
    unsigned* g1      = (unsigned*)alloc((size_t)N * 64 * 4);  // bf16x2, 64 dwords/row
    unsigned* y1      = (unsigned*)alloc((size_t)N * 64 * 4);  // bf16x2
    int*      pairs   = (int*)y1;            // padded bucket regions (12.9 MB < 25.6 MB), dead before y1
    unsigned* g2      = g1;                  // g1 dead after agg1; 32 dwords/row
    float*    out     = (float*)d_out;

    const int nb = (N + 1023) / 1024;

    k_binit<<<1, 256, 0, stream>>>(ccursor, NC);
    k_part<<<PB, 256, 0, stream>>>(src, dst, E, ccursor, pairs, NC);
    k_deg<<<NC, 256, 0, stream>>>(ccursor, pairs, deg, N);
    k_scan_sum<<<nb, 256, 0, stream>>>(deg, N, blks);
    k_scan_blk<<<1, 1, 0, stream>>>(blks, nb);
    k_scan_out<<<nb, 256, 0, stream>>>(deg, N, blks, offsets, dis, E);
    k_place<<<NC, 256, 0, stream>>>(ccursor, offsets, pairs, csr, N);

    // layer 1: g1 = bf16((x @ W1) * dis)
    k_gemm3<128, 512, false><<<(N + 127) / 128, 512, 0, stream>>>(
        (const unsigned char*)x, W1, dis, g1, N);
    k_agg1<<<(N * 64 + 255) / 256, 256, 0, stream>>>(g1, offsets, csr, dis, b1, y1, N);

    // layer 2: g2 = bf16((y1 @ W2) * dis)
    k_gemm3<64, 256, true><<<(N + 127) / 128, 256, 0, stream>>>(
        (const unsigned char*)y1, W2, dis, g2, N);
    k_agg2<<<(N * 64 + 255) / 256, 256, 0, stream>>>(
        g2, offsets, csr, dis, b2, out, N);
}

// Round 6
// 236.394 us; speedup vs baseline: 2.5911x; 1.2529x over previous
//
#include <hip/hip_runtime.h>
#include <hip/hip_bf16.h>
#include <math.h>

#define CSHIFT 9                 // 512 dsts per coarse bucket
#define TILE   4096              // edges per partition block
#define PSH    14                // padded bucket capacity = 16384 (mean fill 8163)

using bf16x8 = __attribute__((ext_vector_type(8))) short;
using f32x4  = __attribute__((ext_vector_type(4))) float;

// ---- bf16 helpers (RNE pack, cheap unpack) ----
__device__ __forceinline__ float bf_lo(unsigned v) { return __uint_as_float(v << 16); }
__device__ __forceinline__ float bf_hi(unsigned v) { return __uint_as_float(v & 0xffff0000u); }
__device__ __forceinline__ unsigned bf_rne(float f) {
    unsigned u = __float_as_uint(f);
    return (u + 0x7fffu + ((u >> 16) & 1u)) >> 16;
}
__device__ __forceinline__ unsigned pack_bf16(float lo, float hi) {
    return bf_rne(lo) | (bf_rne(hi) << 16);
}

// ---------------- bucket cursor init ----------------
__global__ void k_binit(int* __restrict__ ccursor, int NC) {
    int b = blockIdx.x * 256 + threadIdx.x;
    if (b < NC) ccursor[b] = b << PSH;
}

// ---------------- partition pass: LDS hist + chunk reserve + direct scatter ----------------
__global__ __launch_bounds__(256) void k_part(const int* __restrict__ src,
                                              const int* __restrict__ dst, int E,
                                              int* __restrict__ ccursor,
                                              int* __restrict__ pairs, int NC) {
    __shared__ int sdst[TILE];
    __shared__ int h[256], delta[256], cur[256];
    int t = threadIdx.x;
    int base = blockIdx.x * TILE;

    h[t] = 0; __syncthreads();
    #pragma unroll
    for (int k = 0; k < TILE / 256; ++k) {
        int e = base + k * 256 + t;
        int d = (e < E) ? dst[e] : -1;
        sdst[k * 256 + t] = d;
        if (d >= 0) atomicAdd(&h[d >> CSHIFT], 1);
    }
    __syncthreads();
    int myc = h[t];
    int g = 0;
    if (t < NC && myc) g = atomicAdd(&ccursor[t], myc);
    delta[t] = g; cur[t] = 0;
    __syncthreads();

    #pragma unroll
    for (int k = 0; k < TILE / 256; ++k) {
        int e = base + k * 256 + t;
        if (e < E) {
            int d = sdst[k * 256 + t];
            int b = d >> CSHIFT;
            int p = atomicAdd(&cur[b], 1);
            pairs[delta[b] + p] = src[e] | ((d & 511) << 17);
        }
    }
}

// ---------------- per-bucket degree ----------------
__global__ __launch_bounds__(256) void k_deg(const int* __restrict__ ccursor,
                                             const int* __restrict__ pairs,
                                             int* __restrict__ deg, int N) {
    __shared__ int h[512];
    int b = blockIdx.x, t = threadIdx.x;
    h[t] = 0; h[t + 256] = 0; __syncthreads();
    int beg = b << PSH, end = ccursor[b];
    for (int i = beg + t; i < end; i += 256) atomicAdd(&h[pairs[i] >> 17], 1);
    __syncthreads();
    int d0 = b << CSHIFT;
    for (int j = t; j < 512; j += 256) {
        int d = d0 + j;
        if (d < N) deg[d] = h[j];
    }
}

// ---------------- global scan of deg -> offsets, dis ----------------
__global__ void k_scan_sum(const int* __restrict__ deg, int n, int* __restrict__ blksum) {
    __shared__ int sd[256];
    int t = threadIdx.x;
    int base = blockIdx.x * 1024 + t * 4;
    int s = 0;
    if (base + 3 < n) {
        int4 v = *(const int4*)(deg + base);
        s = v.x + v.y + v.z + v.w;
    } else {
        for (int j = 0; j < 4; ++j) if (base + j < n) s += deg[base + j];
    }
    sd[t] = s; __syncthreads();
    for (int o = 128; o > 0; o >>= 1) {
        if (t < o) sd[t] += sd[t + o];
        __syncthreads();
    }
    if (t == 0) blksum[blockIdx.x] = sd[0];
}

__global__ void k_scan_blk(int* blksum, int nb) {
    if (blockIdx.x == 0 && threadIdx.x == 0) {
        int run = 0;
        for (int i = 0; i < nb; ++i) { int v = blksum[i]; blksum[i] = run; run += v; }
    }
}

__global__ void k_scan_out(const int* __restrict__ deg, int n, const int* __restrict__ blkoff,
                           int* __restrict__ offsets, float* __restrict__ dis, int E) {
    __shared__ int sa[256];
    __shared__ int sb[256];
    int t = threadIdx.x;
    int base = blockIdx.x * 1024 + t * 4;
    int v[4]; int s = 0;
    for (int j = 0; j < 4; ++j) {
        int idx = base + j;
        v[j] = (idx < n) ? deg[idx] : 0;
        s += v[j];
    }
    int* cur = sa; int* nxt = sb;
    cur[t] = s; __syncthreads();
    for (int o = 1; o < 256; o <<= 1) {
        int val = cur[t] + ((t >= o) ? cur[t - o] : 0);
        nxt[t] = val; __syncthreads();
        int* tmp = cur; cur = nxt; nxt = tmp;
    }
    int ex = cur[t] - s;
    int run = blkoff[blockIdx.x] + ex;
    for (int j = 0; j < 4; ++j) {
        int idx = base + j;
        if (idx < n) {
            offsets[idx] = run;
            dis[idx] = rsqrtf((float)v[j] + 1.0f);
            run += v[j];
        }
    }
    if (blockIdx.x == 0 && t == 0) offsets[n] = E;
}

// ---------------- final placement ----------------
__global__ __launch_bounds__(256) void k_place(const int* __restrict__ ccursor,
                                               const int* __restrict__ offsets,
                                               const int* __restrict__ pairs,
                                               int* __restrict__ csr, int N) {
    __shared__ int cur[512];
    int b = blockIdx.x, t = threadIdx.x;
    int d0 = b << CSHIFT;
    for (int j = t; j < 512; j += 256) {
        int d = d0 + j;
        cur[j] = (d < N) ? offsets[d] : 0;
    }
    __syncthreads();
    int beg = b << PSH, end = ccursor[b];
    for (int i = beg + t; i < end; i += 256) {
        int pk = pairs[i];
        int p = atomicAdd(&cur[pk >> 17], 1);
        csr[p] = pk & 0x1FFFF;
    }
}

// ---------------- W rearrangement: frag-major bf16 ----------------
// wp[((kt*NT+nt)*64 + l)*8 + e] = bf16(W[kt*32 + (l>>4)*8 + e][nt*16 + (l&15)])
__global__ void k_wprep(const float* __restrict__ W1, const float* __restrict__ W2,
                        unsigned short* __restrict__ wp1, unsigned short* __restrict__ wp2) {
    int idx = blockIdx.x * 256 + threadIdx.x;
    if (idx < 16384) {   // W1: 128x128, NT=8
        int e = idx & 7, l = (idx >> 3) & 63, f = idx >> 9;
        int nt = f & 7, kt = f >> 3;
        int k = kt * 32 + (l >> 4) * 8 + e, nn = nt * 16 + (l & 15);
        wp1[idx] = (unsigned short)bf_rne(W1[k * 128 + nn]);
    }
    int i2 = idx - 16384;
    if (i2 >= 0 && i2 < 8192) {  // W2: 128x64, NT=4
        int e = i2 & 7, l = (i2 >> 3) & 63, f = i2 >> 9;
        int nt = f & 3, kt = f >> 2;
        int k = kt * 32 + (l >> 4) * 8 + e, nn = nt * 16 + (l & 15);
        wp2[i2] = (unsigned short)bf_rne(W2[k * 64 + nn]);
    }
}

// ---------------- MFMA GEMM: G(bf16) = (A @ W) * dis[row] ----------------
// LDS-free, barrier-free. Swapped operands: mfma(A=W-frag, B=x-frag) gives
// D layout col=lane&15 -> output ROW, row=(lane>>4)*4+r -> 4 consecutive
// output COLS per lane -> in-lane bf16 packing + uint2 stores.
template<int NCOL, bool ABF16>
__global__ __launch_bounds__(256) void k_gemm_mfma(
    const void* __restrict__ Aptr, const unsigned short* __restrict__ wp,
    const float* __restrict__ dis, unsigned* __restrict__ G, int M)
{
    constexpr int NT = NCOL / 16;
    constexpr int ND = NCOL / 2;

    union UW { uint4 q; bf16x8 v; };
    union UA { unsigned u[4]; bf16x8 v; };

    const int tid  = threadIdx.x;
    const int wv   = tid >> 6;
    const int lane = tid & 63;
    const int lm   = lane & 15;
    const int lk   = lane >> 4;
    const int m0   = blockIdx.x * 128 + wv * 32;

    // load + convert A fragments (rows of x / y1)
    bf16x8 xf[2][4];
    int mrow[2];
    #pragma unroll
    for (int mt = 0; mt < 2; ++mt) {
        int m = m0 + mt * 16 + lm;
        mrow[mt] = m;
        int mc = m < M ? m : (M - 1);
        if constexpr (ABF16) {
            const uint4* Ar = (const uint4*)((const unsigned short*)Aptr + (size_t)mc * 128);
            #pragma unroll
            for (int kt = 0; kt < 4; ++kt) {
                UW u; u.q = Ar[kt * 4 + lk];
                xf[mt][kt] = u.v;
            }
        } else {
            const float* Ar = (const float*)Aptr + (size_t)mc * 128;
            #pragma unroll
            for (int kt = 0; kt < 4; ++kt) {
                int cb = kt * 32 + lk * 8;
                float4 p = *(const float4*)(Ar + cb);
                float4 q = *(const float4*)(Ar + cb + 4);
                UA u;
                u.u[0] = pack_bf16(p.x, p.y);
                u.u[1] = pack_bf16(p.z, p.w);
                u.u[2] = pack_bf16(q.x, q.y);
                u.u[3] = pack_bf16(q.z, q.w);
                xf[mt][kt] = u.v;
            }
        }
    }

    f32x4 acc[2][NT];
    #pragma unroll
    for (int mt = 0; mt < 2; ++mt)
        #pragma unroll
        for (int nt = 0; nt < NT; ++nt)
            #pragma unroll
            for (int r = 0; r < 4; ++r) acc[mt][nt][r] = 0.f;

    const uint4* wpv = (const uint4*)wp;
    #pragma unroll
    for (int kt = 0; kt < 4; ++kt) {
        bf16x8 wf[NT];
        #pragma unroll
        for (int nt = 0; nt < NT; ++nt) {
            UW u; u.q = wpv[(kt * NT + nt) * 64 + lane];
            wf[nt] = u.v;
        }
        #pragma unroll
        for (int mt = 0; mt < 2; ++mt)
            #pragma unroll
            for (int nt = 0; nt < NT; ++nt)
                acc[mt][nt] = __builtin_amdgcn_mfma_f32_16x16x32_bf16(
                    wf[nt], xf[mt][kt], acc[mt][nt], 0, 0, 0);
    }

    #pragma unroll
    for (int mt = 0; mt < 2; ++mt) {
        int m = mrow[mt];
        if (m < M) {
            float dd = dis[m];
            unsigned* gr = G + (size_t)m * ND;
            #pragma unroll
            for (int nt = 0; nt < NT; ++nt) {
                uint2 w;
                w.x = pack_bf16(acc[mt][nt][0] * dd, acc[mt][nt][1] * dd);
                w.y = pack_bf16(acc[mt][nt][2] * dd, acc[mt][nt][3] * dd);
                *(uint2*)(gr + nt * 8 + lk * 2) = w;
            }
        }
    }
}

// ---------------- aggregation layer 1: full wave per dst, 8-deep unroll ----------------
__global__ __launch_bounds__(256) void k_agg1(
    const unsigned* __restrict__ g1, const int* __restrict__ offsets,
    const int* __restrict__ csr_src, const float* __restrict__ dis,
    const float* __restrict__ b1, unsigned* __restrict__ y1, int n)
{
    int wid  = (blockIdx.x * 256 + threadIdx.x) >> 6;
    int lane = threadIdx.x & 63;
    if (wid >= n) return;
    int d = wid;
    int beg = offsets[d], end = offsets[d + 1];

    unsigned sv = g1[(size_t)d * 64 + lane];
    float ax = bf_lo(sv), ay = bf_hi(sv);
    int j = beg;
    for (; j + 8 <= end; j += 8) {
        unsigned v0 = g1[(size_t)csr_src[j    ] * 64 + lane];
        unsigned v1 = g1[(size_t)csr_src[j + 1] * 64 + lane];
        unsigned v2 = g1[(size_t)csr_src[j + 2] * 64 + lane];
        unsigned v3 = g1[(size_t)csr_src[j + 3] * 64 + lane];
        unsigned v4 = g1[(size_t)csr_src[j + 4] * 64 + lane];
        unsigned v5 = g1[(size_t)csr_src[j + 5] * 64 + lane];
        unsigned v6 = g1[(size_t)csr_src[j + 6] * 64 + lane];
        unsigned v7 = g1[(size_t)csr_src[j + 7] * 64 + lane];
        ax += bf_lo(v0) + bf_lo(v1) + bf_lo(v2) + bf_lo(v3)
            + bf_lo(v4) + bf_lo(v5) + bf_lo(v6) + bf_lo(v7);
        ay += bf_hi(v0) + bf_hi(v1) + bf_hi(v2) + bf_hi(v3)
            + bf_hi(v4) + bf_hi(v5) + bf_hi(v6) + bf_hi(v7);
    }
    for (; j < end; ++j) {
        unsigned v = g1[(size_t)csr_src[j] * 64 + lane];
        ax += bf_lo(v); ay += bf_hi(v);
    }
    float dd = dis[d];
    float2 bb = ((const float2*)b1)[lane];
    float ox = fmaxf(fmaf(dd, ax, bb.x), 0.f);
    float oy = fmaxf(fmaf(dd, ay, bb.y), 0.f);
    y1[(size_t)d * 64 + lane] = pack_bf16(ox, oy);
}

// ---------------- aggregation layer 2 + L2 normalize: quarter-wave per edge ----------------
__global__ __launch_bounds__(256) void k_agg2(
    const unsigned* __restrict__ g2, const int* __restrict__ offsets,
    const int* __restrict__ csr_src, const float* __restrict__ dis,
    const float* __restrict__ b2, float* __restrict__ out, int n)
{
    int wid  = (blockIdx.x * 256 + threadIdx.x) >> 6;
    int lane = threadIdx.x & 63;
    if (wid >= n) return;
    int d  = wid;
    int ql = lane & 15;
    int qh = lane >> 4;
    int beg = offsets[d], end = offsets[d + 1];

    float a0 = 0.f, a1 = 0.f, a2 = 0.f, a3 = 0.f;
    int j = beg;
    for (; j + 8 <= end; j += 8) {
        int sA = csr_src[j + qh];
        int sB = csr_src[j + 4 + qh];
        uint2 vA = *((const uint2*)(g2 + (size_t)sA * 32) + ql);
        uint2 vB = *((const uint2*)(g2 + (size_t)sB * 32) + ql);
        a0 += bf_lo(vA.x) + bf_lo(vB.x);
        a1 += bf_hi(vA.x) + bf_hi(vB.x);
        a2 += bf_lo(vA.y) + bf_lo(vB.y);
        a3 += bf_hi(vA.y) + bf_hi(vB.y);
    }
    for (; j < end; j += 4) {
        if (j + qh < end) {
            int s = csr_src[j + qh];
            uint2 v = *((const uint2*)(g2 + (size_t)s * 32) + ql);
            a0 += bf_lo(v.x); a1 += bf_hi(v.x);
            a2 += bf_lo(v.y); a3 += bf_hi(v.y);
        }
    }
    a0 += __shfl_xor(a0, 16, 64); a0 += __shfl_xor(a0, 32, 64);
    a1 += __shfl_xor(a1, 16, 64); a1 += __shfl_xor(a1, 32, 64);
    a2 += __shfl_xor(a2, 16, 64); a2 += __shfl_xor(a2, 32, 64);
    a3 += __shfl_xor(a3, 16, 64); a3 += __shfl_xor(a3, 32, 64);
    uint2 sv = *((const uint2*)(g2 + (size_t)d * 32) + ql);
    a0 += bf_lo(sv.x); a1 += bf_hi(sv.x);
    a2 += bf_lo(sv.y); a3 += bf_hi(sv.y);

    float dd = dis[d];
    float4 bb = *(const float4*)(b2 + 4 * ql);
    float v0 = fmaf(dd, a0, bb.x);
    float v1 = fmaf(dd, a1, bb.y);
    float v2 = fmaf(dd, a2, bb.z);
    float v3 = fmaf(dd, a3, bb.w);

    float ss = v0 * v0 + v1 * v1 + v2 * v2 + v3 * v3;
    #pragma unroll
    for (int o = 8; o >= 1; o >>= 1)
        ss += __shfl_xor(ss, o, 64);
    float inv = 1.0f / fmaxf(sqrtf(ss), 1e-12f);
    if (lane < 16) {
        float4 w = make_float4(v0 * inv, v1 * inv, v2 * inv, v3 * inv);
        *((float4*)(out + (size_t)d * 64) + ql) = w;
    }
}

// ---------------- launcher ----------------
extern "C" void kernel_launch(void* const* d_in, const int* in_sizes, int n_in,
                              void* d_out, int out_size, void* d_ws, size_t ws_size,
                              hipStream_t stream) {
    const float* x  = (const float*)d_in[0];
    const int*   ei = (const int*)d_in[1];
    const float* W1 = (const float*)d_in[2];
    const float* b1 = (const float*)d_in[3];
    const float* W2 = (const float*)d_in[4];
    const float* b2 = (const float*)d_in[5];

    const int N = in_sizes[0] / 128;   // 100000
    const int E = in_sizes[1] / 2;     // 1600000
    const int* src = ei;
    const int* dst = ei + E;
    const int NC = (N + 511) >> CSHIFT;          // 196 coarse buckets
    const int PB = (E + TILE - 1) / TILE;        // 391 partition blocks

    char* ws = (char*)d_ws;
    size_t cur = 0;
    auto alloc = [&](size_t bytes) -> void* {
        void* p = ws + cur;
        cur += (bytes + 255) & ~(size_t)255;
        return p;
    };
    int*            deg     = (int*)            alloc((size_t)N * 4);
    int*            offsets = (int*)            alloc((size_t)(N + 1) * 4);
    int*            ccursor = (int*)            alloc((size_t)NC * 4);
    int*            blks    = (int*)            alloc(4096);
    float*          dis     = (float*)          alloc((size_t)N * 4);
    int*            csr     = (int*)            alloc((size_t)E * 4);
    unsigned short* wp1     = (unsigned short*) alloc(16384 * 2);
    unsigned short* wp2     = (unsigned short*) alloc(8192 * 2);
    unsigned*       g1      = (unsigned*)       alloc((size_t)N * 64 * 4);  // bf16x2
    unsigned*       y1      = (unsigned*)       alloc((size_t)N * 64 * 4);  // bf16x2
    int*            pairs   = (int*)y1;          // padded bucket regions, dead before y1
    unsigned*       g2      = g1;                // g1 dead after agg1; 32 dwords/row
    float*          out     = (float*)d_out;

    const int nb = (N + 1023) / 1024;

    k_wprep<<<96, 256, 0, stream>>>(W1, W2, wp1, wp2);
    k_binit<<<1, 256, 0, stream>>>(ccursor, NC);
    k_part<<<PB, 256, 0, stream>>>(src, dst, E, ccursor, pairs, NC);
    k_deg<<<NC, 256, 0, stream>>>(ccursor, pairs, deg, N);
    k_scan_sum<<<nb, 256, 0, stream>>>(deg, N, blks);
    k_scan_blk<<<1, 1, 0, stream>>>(blks, nb);
    k_scan_out<<<nb, 256, 0, stream>>>(deg, N, blks, offsets, dis, E);
    k_place<<<NC, 256, 0, stream>>>(ccursor, offsets, pairs, csr, N);

    // layer 1: g1 = bf16((x @ W1) * dis)   [MFMA]
    k_gemm_mfma<128, false><<<(N + 127) / 128, 256, 0, stream>>>(x, wp1, dis, g1, N);
    k_agg1<<<(N * 64 + 255) / 256, 256, 0, stream>>>(g1, offsets, csr, dis, b1, y1, N);

    // layer 2: g2 = bf16((y1 @ W2) * dis)  [MFMA]
    k_gemm_mfma<64, true><<<(N + 127) / 128, 256, 0, stream>>>(y1, wp2, dis, g2, N);
    k_agg2<<<(N * 64 + 255) / 256, 256, 0, stream>>>(g2, offsets, csr, dis, b2, out, N);
}

// Round 7
// 221.222 us; speedup vs baseline: 2.7688x; 1.0686x over previous
//
#include <hip/hip_runtime.h>
#include <hip/hip_bf16.h>
#include <math.h>

#define CSHIFT 9                 // 512 dsts per coarse bucket
#define TILE   4096              // edges per partition block
#define PSH    14                // padded bucket capacity = 16384 (mean fill 8163)

using bf16x8 = __attribute__((ext_vector_type(8))) short;
using f32x4  = __attribute__((ext_vector_type(4))) float;

// ---- bf16 helpers (RNE pack, cheap unpack) ----
__device__ __forceinline__ float bf_lo(unsigned v) { return __uint_as_float(v << 16); }
__device__ __forceinline__ float bf_hi(unsigned v) { return __uint_as_float(v & 0xffff0000u); }
__device__ __forceinline__ unsigned bf_rne(float f) {
    unsigned u = __float_as_uint(f);
    return (u + 0x7fffu + ((u >> 16) & 1u)) >> 16;
}
__device__ __forceinline__ unsigned pack_bf16(float lo, float hi) {
    return bf_rne(lo) | (bf_rne(hi) << 16);
}

// ---------------- W rearrangement (frag-major bf16) + bucket cursor init ----------------
__global__ void k_prep(const float* __restrict__ W1, const float* __restrict__ W2,
                       unsigned short* __restrict__ wp1, unsigned short* __restrict__ wp2,
                       int* __restrict__ ccursor, int NC) {
    int idx = blockIdx.x * 256 + threadIdx.x;
    if (idx < NC) ccursor[idx] = idx << PSH;
    if (idx < 16384) {   // W1: 128x128, NT=8
        int e = idx & 7, l = (idx >> 3) & 63, f = idx >> 9;
        int nt = f & 7, kt = f >> 3;
        int k = kt * 32 + (l >> 4) * 8 + e, nn = nt * 16 + (l & 15);
        wp1[idx] = (unsigned short)bf_rne(W1[k * 128 + nn]);
    }
    int i2 = idx - 16384;
    if (i2 >= 0 && i2 < 8192) {  // W2: 128x64, NT=4
        int e = i2 & 7, l = (i2 >> 3) & 63, f = i2 >> 9;
        int nt = f & 3, kt = f >> 2;
        int k = kt * 32 + (l >> 4) * 8 + e, nn = nt * 16 + (l & 15);
        wp2[i2] = (unsigned short)bf_rne(W2[k * 64 + nn]);
    }
}

// ---------------- partition pass: LDS hist + chunk reserve + direct scatter ----------------
__global__ __launch_bounds__(256) void k_part(const int* __restrict__ src,
                                              const int* __restrict__ dst, int E,
                                              int* __restrict__ ccursor,
                                              int* __restrict__ pairs, int NC) {
    __shared__ int sdst[TILE];
    __shared__ int h[256], delta[256], cur[256];
    int t = threadIdx.x;
    int base = blockIdx.x * TILE;

    h[t] = 0; __syncthreads();
    #pragma unroll
    for (int k = 0; k < TILE / 256; ++k) {
        int e = base + k * 256 + t;
        int d = (e < E) ? dst[e] : -1;
        sdst[k * 256 + t] = d;
        if (d >= 0) atomicAdd(&h[d >> CSHIFT], 1);
    }
    __syncthreads();
    int myc = h[t];
    int g = 0;
    if (t < NC && myc) g = atomicAdd(&ccursor[t], myc);
    delta[t] = g; cur[t] = 0;
    __syncthreads();

    #pragma unroll
    for (int k = 0; k < TILE / 256; ++k) {
        int e = base + k * 256 + t;
        if (e < E) {
            int d = sdst[k * 256 + t];
            int b = d >> CSHIFT;
            int p = atomicAdd(&cur[b], 1);
            pairs[delta[b] + p] = src[e] | ((d & 511) << 17);
        }
    }
}

// ---------------- bucket-base scan (196 entries, from ccursor fill levels) ----------------
__global__ void k_sblk(const int* __restrict__ ccursor, int* __restrict__ blkoff, int NC) {
    if (blockIdx.x == 0 && threadIdx.x == 0) {
        int run = 0;
        for (int b = 0; b < NC; ++b) {
            blkoff[b] = run;
            run += ccursor[b] - (b << PSH);
        }
    }
}

// ---------------- per-bucket degree + intra-bucket scan + dis ----------------
__global__ __launch_bounds__(256) void k_deg(const int* __restrict__ ccursor,
                                             const int* __restrict__ pairs,
                                             int* __restrict__ lofs,
                                             float* __restrict__ dis, int N) {
    __shared__ int h[512];
    __shared__ int sa[256], sb[256];
    int b = blockIdx.x, t = threadIdx.x;
    h[t] = 0; h[t + 256] = 0; __syncthreads();
    int beg = b << PSH, end = ccursor[b];
    for (int i = beg + t; i < end; i += 256) atomicAdd(&h[pairs[i] >> 17], 1);
    __syncthreads();
    int h0 = h[2 * t], h1 = h[2 * t + 1];
    int s = h0 + h1;
    int* cur = sa; int* nxt = sb;
    cur[t] = s; __syncthreads();
    for (int o = 1; o < 256; o <<= 1) {
        int val = cur[t] + ((t >= o) ? cur[t - o] : 0);
        nxt[t] = val; __syncthreads();
        int* tmp = cur; cur = nxt; nxt = tmp;
    }
    int ex = cur[t] - s;
    int d0 = b << CSHIFT;
    int da = d0 + 2 * t, db = da + 1;
    lofs[da] = ex;
    lofs[db] = ex + h0;
    if (da < N) dis[da] = rsqrtf((float)h0 + 1.0f);
    if (db < N) dis[db] = rsqrtf((float)h1 + 1.0f);
}

// ---------------- finish: offsets[d] = lofs[d] + blkoff[d>>9] ----------------
__global__ void k_scan_fin(const int* __restrict__ lofs, const int* __restrict__ blkoff,
                           int* __restrict__ offsets, int N, int E) {
    int base = blockIdx.x * 1024 + threadIdx.x * 4;
    if (base < N) {
        int bo = blkoff[base >> CSHIFT];
        if (base + 3 < N) {
            int4 v = *(const int4*)(lofs + base);
            v.x += bo; v.y += bo; v.z += bo; v.w += bo;
            *(int4*)(offsets + base) = v;
        } else {
            for (int j = 0; j < 4 && base + j < N; ++j)
                offsets[base + j] = lofs[base + j] + bo;
        }
    }
    if (blockIdx.x == 0 && threadIdx.x == 0) offsets[N] = E;
}

// ---------------- final placement ----------------
__global__ __launch_bounds__(256) void k_place(const int* __restrict__ ccursor,
                                               const int* __restrict__ offsets,
                                               const int* __restrict__ pairs,
                                               int* __restrict__ csr, int N) {
    __shared__ int cur[512];
    int b = blockIdx.x, t = threadIdx.x;
    int d0 = b << CSHIFT;
    for (int j = t; j < 512; j += 256) {
        int d = d0 + j;
        cur[j] = (d < N) ? offsets[d] : 0;
    }
    __syncthreads();
    int beg = b << PSH, end = ccursor[b];
    for (int i = beg + t; i < end; i += 256) {
        int pk = pairs[i];
        int p = atomicAdd(&cur[pk >> 17], 1);
        csr[p] = pk & 0x1FFFF;
    }
}

// ---------------- MFMA GEMM: G(bf16) = (A @ W) * dis[row] ----------------
template<int NCOL, bool ABF16>
__global__ __launch_bounds__(256) void k_gemm_mfma(
    const void* __restrict__ Aptr, const unsigned short* __restrict__ wp,
    const float* __restrict__ dis, unsigned* __restrict__ G, int M)
{
    constexpr int NT = NCOL / 16;
    constexpr int ND = NCOL / 2;

    union UW { uint4 q; bf16x8 v; };
    union UA { unsigned u[4]; bf16x8 v; };

    const int tid  = threadIdx.x;
    const int wv   = tid >> 6;
    const int lane = tid & 63;
    const int lm   = lane & 15;
    const int lk   = lane >> 4;
    const int m0   = blockIdx.x * 128 + wv * 32;

    bf16x8 xf[2][4];
    int mrow[2];
    #pragma unroll
    for (int mt = 0; mt < 2; ++mt) {
        int m = m0 + mt * 16 + lm;
        mrow[mt] = m;
        int mc = m < M ? m : (M - 1);
        if constexpr (ABF16) {
            const uint4* Ar = (const uint4*)((const unsigned short*)Aptr + (size_t)mc * 128);
            #pragma unroll
            for (int kt = 0; kt < 4; ++kt) {
                UW u; u.q = Ar[kt * 4 + lk];
                xf[mt][kt] = u.v;
            }
        } else {
            const float* Ar = (const float*)Aptr + (size_t)mc * 128;
            #pragma unroll
            for (int kt = 0; kt < 4; ++kt) {
                int cb = kt * 32 + lk * 8;
                float4 p = *(const float4*)(Ar + cb);
                float4 q = *(const float4*)(Ar + cb + 4);
                UA u;
                u.u[0] = pack_bf16(p.x, p.y);
                u.u[1] = pack_bf16(p.z, p.w);
                u.u[2] = pack_bf16(q.x, q.y);
                u.u[3] = pack_bf16(q.z, q.w);
                xf[mt][kt] = u.v;
            }
        }
    }

    f32x4 acc[2][NT];
    #pragma unroll
    for (int mt = 0; mt < 2; ++mt)
        #pragma unroll
        for (int nt = 0; nt < NT; ++nt)
            #pragma unroll
            for (int r = 0; r < 4; ++r) acc[mt][nt][r] = 0.f;

    const uint4* wpv = (const uint4*)wp;
    #pragma unroll
    for (int kt = 0; kt < 4; ++kt) {
        bf16x8 wf[NT];
        #pragma unroll
        for (int nt = 0; nt < NT; ++nt) {
            UW u; u.q = wpv[(kt * NT + nt) * 64 + lane];
            wf[nt] = u.v;
        }
        #pragma unroll
        for (int mt = 0; mt < 2; ++mt)
            #pragma unroll
            for (int nt = 0; nt < NT; ++nt)
                acc[mt][nt] = __builtin_amdgcn_mfma_f32_16x16x32_bf16(
                    wf[nt], xf[mt][kt], acc[mt][nt], 0, 0, 0);
    }

    #pragma unroll
    for (int mt = 0; mt < 2; ++mt) {
        int m = mrow[mt];
        if (m < M) {
            float dd = dis[m];
            unsigned* gr = G + (size_t)m * ND;
            #pragma unroll
            for (int nt = 0; nt < NT; ++nt) {
                uint2 w;
                w.x = pack_bf16(acc[mt][nt][0] * dd, acc[mt][nt][1] * dd);
                w.y = pack_bf16(acc[mt][nt][2] * dd, acc[mt][nt][3] * dd);
                *(uint2*)(gr + nt * 8 + lk * 2) = w;
            }
        }
    }
}

// ---------------- aggregation layer 1: full wave per dst, 16-deep unroll ----------------
__global__ __launch_bounds__(256) void k_agg1(
    const unsigned* __restrict__ g1, const int* __restrict__ offsets,
    const int* __restrict__ csr_src, const float* __restrict__ dis,
    const float* __restrict__ b1, unsigned* __restrict__ y1, int n)
{
    int wid  = (blockIdx.x * 256 + threadIdx.x) >> 6;
    int lane = threadIdx.x & 63;
    if (wid >= n) return;
    int d = wid;
    int beg = offsets[d], end = offsets[d + 1];

    unsigned sv = g1[(size_t)d * 64 + lane];
    float ax = bf_lo(sv), ay = bf_hi(sv);
    int j = beg;
    for (; j + 16 <= end; j += 16) {
        unsigned v[16];
        #pragma unroll
        for (int k = 0; k < 16; ++k)
            v[k] = g1[(size_t)csr_src[j + k] * 64 + lane];
        #pragma unroll
        for (int k = 0; k < 16; ++k) { ax += bf_lo(v[k]); ay += bf_hi(v[k]); }
    }
    for (; j + 4 <= end; j += 4) {
        unsigned v0 = g1[(size_t)csr_src[j    ] * 64 + lane];
        unsigned v1 = g1[(size_t)csr_src[j + 1] * 64 + lane];
        unsigned v2 = g1[(size_t)csr_src[j + 2] * 64 + lane];
        unsigned v3 = g1[(size_t)csr_src[j + 3] * 64 + lane];
        ax += bf_lo(v0) + bf_lo(v1) + bf_lo(v2) + bf_lo(v3);
        ay += bf_hi(v0) + bf_hi(v1) + bf_hi(v2) + bf_hi(v3);
    }
    for (; j < end; ++j) {
        unsigned v = g1[(size_t)csr_src[j] * 64 + lane];
        ax += bf_lo(v); ay += bf_hi(v);
    }
    float dd = dis[d];
    float2 bb = ((const float2*)b1)[lane];
    float ox = fmaxf(fmaf(dd, ax, bb.x), 0.f);
    float oy = fmaxf(fmaf(dd, ay, bb.y), 0.f);
    y1[(size_t)d * 64 + lane] = pack_bf16(ox, oy);
}

// ---------------- aggregation layer 2 + L2 normalize: quarter-wave per edge ----------------
__global__ __launch_bounds__(256) void k_agg2(
    const unsigned* __restrict__ g2, const int* __restrict__ offsets,
    const int* __restrict__ csr_src, const float* __restrict__ dis,
    const float* __restrict__ b2, float* __restrict__ out, int n)
{
    int wid  = (blockIdx.x * 256 + threadIdx.x) >> 6;
    int lane = threadIdx.x & 63;
    if (wid >= n) return;
    int d  = wid;
    int ql = lane & 15;
    int qh = lane >> 4;
    int beg = offsets[d], end = offsets[d + 1];

    float a0 = 0.f, a1 = 0.f, a2 = 0.f, a3 = 0.f;
    int j = beg;
    for (; j + 16 <= end; j += 16) {
        int s0 = csr_src[j      + qh];
        int s1 = csr_src[j + 4  + qh];
        int s2 = csr_src[j + 8  + qh];
        int s3 = csr_src[j + 12 + qh];
        uint2 v0 = *((const uint2*)(g2 + (size_t)s0 * 32) + ql);
        uint2 v1 = *((const uint2*)(g2 + (size_t)s1 * 32) + ql);
        uint2 v2 = *((const uint2*)(g2 + (size_t)s2 * 32) + ql);
        uint2 v3 = *((const uint2*)(g2 + (size_t)s3 * 32) + ql);
        a0 += bf_lo(v0.x) + bf_lo(v1.x) + bf_lo(v2.x) + bf_lo(v3.x);
        a1 += bf_hi(v0.x) + bf_hi(v1.x) + bf_hi(v2.x) + bf_hi(v3.x);
        a2 += bf_lo(v0.y) + bf_lo(v1.y) + bf_lo(v2.y) + bf_lo(v3.y);
        a3 += bf_hi(v0.y) + bf_hi(v1.y) + bf_hi(v2.y) + bf_hi(v3.y);
    }
    for (; j < end; j += 4) {
        if (j + qh < end) {
            int s = csr_src[j + qh];
            uint2 v = *((const uint2*)(g2 + (size_t)s * 32) + ql);
            a0 += bf_lo(v.x); a1 += bf_hi(v.x);
            a2 += bf_lo(v.y); a3 += bf_hi(v.y);
        }
    }
    a0 += __shfl_xor(a0, 16, 64); a0 += __shfl_xor(a0, 32, 64);
    a1 += __shfl_xor(a1, 16, 64); a1 += __shfl_xor(a1, 32, 64);
    a2 += __shfl_xor(a2, 16, 64); a2 += __shfl_xor(a2, 32, 64);
    a3 += __shfl_xor(a3, 16, 64); a3 += __shfl_xor(a3, 32, 64);
    uint2 sv = *((const uint2*)(g2 + (size_t)d * 32) + ql);
    a0 += bf_lo(sv.x); a1 += bf_hi(sv.x);
    a2 += bf_lo(sv.y); a3 += bf_hi(sv.y);

    float dd = dis[d];
    float4 bb = *(const float4*)(b2 + 4 * ql);
    float v0 = fmaf(dd, a0, bb.x);
    float v1 = fmaf(dd, a1, bb.y);
    float v2 = fmaf(dd, a2, bb.z);
    float v3 = fmaf(dd, a3, bb.w);

    float ss = v0 * v0 + v1 * v1 + v2 * v2 + v3 * v3;
    #pragma unroll
    for (int o = 8; o >= 1; o >>= 1)
        ss += __shfl_xor(ss, o, 64);
    float inv = 1.0f / fmaxf(sqrtf(ss), 1e-12f);
    if (lane < 16) {
        float4 w = make_float4(v0 * inv, v1 * inv, v2 * inv, v3 * inv);
        *((float4*)(out + (size_t)d * 64) + ql) = w;
    }
}

// ---------------- launcher ----------------
extern "C" void kernel_launch(void* const* d_in, const int* in_sizes, int n_in,
                              void* d_out, int out_size, void* d_ws, size_t ws_size,
                              hipStream_t stream) {
    const float* x  = (const float*)d_in[0];
    const int*   ei = (const int*)d_in[1];
    const float* W1 = (const float*)d_in[2];
    const float* b1 = (const float*)d_in[3];
    const float* W2 = (const float*)d_in[4];
    const float* b2 = (const float*)d_in[5];

    const int N = in_sizes[0] / 128;   // 100000
    const int E = in_sizes[1] / 2;     // 1600000
    const int* src = ei;
    const int* dst = ei + E;
    const int NC = (N + 511) >> CSHIFT;          // 196 coarse buckets
    const int PB = (E + TILE - 1) / TILE;        // 391 partition blocks

    char* ws = (char*)d_ws;
    size_t cur = 0;
    auto alloc = [&](size_t bytes) -> void* {
        void* p = ws + cur;
        cur += (bytes + 255) & ~(size_t)255;
        return p;
    };
    int*            lofs    = (int*)            alloc((size_t)NC * 512 * 4);
    int*            offsets = (int*)            alloc((size_t)(N + 1) * 4);
    int*            ccursor = (int*)            alloc((size_t)NC * 4);
    int*            blkoff  = (int*)            alloc((size_t)(NC + 1) * 4);
    float*          dis     = (float*)          alloc((size_t)N * 4);
    int*            csr     = (int*)            alloc((size_t)E * 4);
    unsigned short* wp1     = (unsigned short*) alloc(16384 * 2);
    unsigned short* wp2     = (unsigned short*) alloc(8192 * 2);
    unsigned*       g1      = (unsigned*)       alloc((size_t)N * 64 * 4);  // bf16x2
    unsigned*       y1      = (unsigned*)       alloc((size_t)N * 64 * 4);  // bf16x2
    int*            pairs   = (int*)y1;          // padded bucket regions (12.9 MB), dead before y1
    unsigned*       g2      = g1;                // g1 dead after agg1; 32 dwords/row
    float*          out     = (float*)d_out;

    k_prep<<<96, 256, 0, stream>>>(W1, W2, wp1, wp2, ccursor, NC);
    k_part<<<PB, 256, 0, stream>>>(src, dst, E, ccursor, pairs, NC);
    k_sblk<<<1, 1, 0, stream>>>(ccursor, blkoff, NC);
    k_deg<<<NC, 256, 0, stream>>>(ccursor, pairs, lofs, dis, N);
    k_scan_fin<<<(N + 1023) / 1024, 256, 0, stream>>>(lofs, blkoff, offsets, N, E);
    k_place<<<NC, 256, 0, stream>>>(ccursor, offsets, pairs, csr, N);

    // layer 1: g1 = bf16((x @ W1) * dis)   [MFMA]
    k_gemm_mfma<128, false><<<(N + 127) / 128, 256, 0, stream>>>(x, wp1, dis, g1, N);
    k_agg1<<<(N * 64 + 255) / 256, 256, 0, stream>>>(g1, offsets, csr, dis, b1, y1, N);

    // layer 2: g2 = bf16((y1 @ W2) * dis)  [MFMA]
    k_gemm_mfma<64, true><<<(N + 127) / 128, 256, 0, stream>>>(y1, wp2, dis, g2, N);
    k_agg2<<<(N * 64 + 255) / 256, 256, 0, stream>>>(g2, offsets, csr, dis, b2, out, N);
}

// Round 9
// 202.167 us; speedup vs baseline: 3.0297x; 1.0943x over previous
//
#include <hip/hip_runtime.h>
#include <hip/hip_bf16.h>
#include <math.h>

#define CSHIFT 9                 // 512 dsts per coarse bucket
#define TILE   4096              // edges per partition block
#define PSH    14                // padded bucket capacity = 16384 (mean fill 8163)

using f16x8 = __attribute__((ext_vector_type(8))) _Float16;
using f16x2 = __attribute__((ext_vector_type(2))) _Float16;
using f32x4 = __attribute__((ext_vector_type(4))) float;

// ---- fp16 helpers ----
__device__ __forceinline__ unsigned pack_f16(float lo, float hi) {
    auto h = __builtin_amdgcn_cvt_pkrtz(lo, hi);   // __fp16 ext_vector(2)
    return *(unsigned*)&h;
}
__device__ __forceinline__ f16x2 h2(unsigned u) { return *(f16x2*)&u; }

// ---------------- W rearrangement (frag-major fp16) + bucket cursor init ----------------
__global__ void k_prep(const float* __restrict__ W1, const float* __restrict__ W2,
                       unsigned short* __restrict__ wp1, unsigned short* __restrict__ wp2,
                       int* __restrict__ ccursor, int NC) {
    int idx = blockIdx.x * 256 + threadIdx.x;
    if (idx < NC) ccursor[idx] = idx << PSH;
    if (idx < 16384) {   // W1: 128x128, NT=8
        int e = idx & 7, l = (idx >> 3) & 63, f = idx >> 9;
        int nt = f & 7, kt = f >> 3;
        int k = kt * 32 + (l >> 4) * 8 + e, nn = nt * 16 + (l & 15);
        _Float16 hv = (_Float16)W1[k * 128 + nn];
        wp1[idx] = *(unsigned short*)&hv;
    }
    int i2 = idx - 16384;
    if (i2 >= 0 && i2 < 8192) {  // W2: 128x64, NT=4
        int e = i2 & 7, l = (i2 >> 3) & 63, f = i2 >> 9;
        int nt = f & 3, kt = f >> 2;
        int k = kt * 32 + (l >> 4) * 8 + e, nn = nt * 16 + (l & 15);
        _Float16 hv = (_Float16)W2[k * 64 + nn];
        wp2[i2] = *(unsigned short*)&hv;
    }
}

// ---------------- partition pass: LDS hist + chunk reserve + direct scatter ----------------
__global__ __launch_bounds__(256) void k_part(const int* __restrict__ src,
                                              const int* __restrict__ dst, int E,
                                              int* __restrict__ ccursor,
                                              int* __restrict__ pairs, int NC) {
    __shared__ int sdst[TILE];
    __shared__ int h[256], delta[256], cur[256];
    int t = threadIdx.x;
    int base = blockIdx.x * TILE;

    h[t] = 0; __syncthreads();
    #pragma unroll
    for (int k = 0; k < TILE / 256; ++k) {
        int e = base + k * 256 + t;
        int d = (e < E) ? dst[e] : -1;
        sdst[k * 256 + t] = d;
        if (d >= 0) atomicAdd(&h[d >> CSHIFT], 1);
    }
    __syncthreads();
    int myc = h[t];
    int g = 0;
    if (t < NC && myc) g = atomicAdd(&ccursor[t], myc);
    delta[t] = g; cur[t] = 0;
    __syncthreads();

    #pragma unroll
    for (int k = 0; k < TILE / 256; ++k) {
        int e = base + k * 256 + t;
        if (e < E) {
            int d = sdst[k * 256 + t];
            int b = d >> CSHIFT;
            int p = atomicAdd(&cur[b], 1);
            pairs[delta[b] + p] = src[e] | ((d & 511) << 17);
        }
    }
}

// ---------------- fused degree + scan + dis + placement (per bucket) ----------------
__global__ __launch_bounds__(256) void k_build(const int* __restrict__ ccursor,
                                               const int* __restrict__ pairs,
                                               int2* __restrict__ seg,
                                               float* __restrict__ dis,
                                               int* __restrict__ csr, int N) {
    __shared__ int h[512];
    __shared__ int cur[512];
    __shared__ int sa[256], sb[256];
    int b = blockIdx.x, t = threadIdx.x;
    h[t] = 0; h[t + 256] = 0; __syncthreads();
    int beg = b << PSH, end = ccursor[b];
    for (int i = beg + t; i < end; i += 256) atomicAdd(&h[pairs[i] >> 17], 1);
    __syncthreads();
    int h0 = h[2 * t], h1 = h[2 * t + 1];
    int s = h0 + h1;
    int* c_ = sa; int* n_ = sb;
    c_[t] = s; __syncthreads();
    for (int o = 1; o < 256; o <<= 1) {
        int val = c_[t] + ((t >= o) ? c_[t - o] : 0);
        n_[t] = val; __syncthreads();
        int* tmp = c_; c_ = n_; n_ = tmp;
    }
    int ex = c_[t] - s;
    int d0 = b << CSHIFT;
    int da = d0 + 2 * t, db = da + 1;
    cur[2 * t] = ex; cur[2 * t + 1] = ex + h0;
    if (da < N) { seg[da] = make_int2(beg + ex, beg + ex + h0); dis[da] = rsqrtf((float)h0 + 1.0f); }
    if (db < N) { seg[db] = make_int2(beg + ex + h0, beg + ex + h0 + h1); dis[db] = rsqrtf((float)h1 + 1.0f); }
    __syncthreads();
    for (int i = beg + t; i < end; i += 256) {
        int pk = pairs[i];
        int p = atomicAdd(&cur[pk >> 17], 1);
        csr[beg + p] = pk & 0x1FFFF;
    }
}

// ---------------- MFMA GEMM (f16): G(fp16) = (A @ W) * dis[row] ----------------
template<int NCOL, bool AHALF>
__global__ __launch_bounds__(256) void k_gemm_mfma(
    const void* __restrict__ Aptr, const unsigned short* __restrict__ wp,
    const float* __restrict__ dis, unsigned* __restrict__ G, int M)
{
    constexpr int NT = NCOL / 16;
    constexpr int ND = NCOL / 2;

    union UW { uint4 q; f16x8 v; };
    union UA { unsigned u[4]; f16x8 v; };

    const int tid  = threadIdx.x;
    const int wv   = tid >> 6;
    const int lane = tid & 63;
    const int lm   = lane & 15;
    const int lk   = lane >> 4;
    const int m0   = blockIdx.x * 128 + wv * 32;

    f16x8 xf[2][4];
    int mrow[2];
    #pragma unroll
    for (int mt = 0; mt < 2; ++mt) {
        int m = m0 + mt * 16 + lm;
        mrow[mt] = m;
        int mc = m < M ? m : (M - 1);
        if constexpr (AHALF) {
            const uint4* Ar = (const uint4*)((const unsigned short*)Aptr + (size_t)mc * 128);
            #pragma unroll
            for (int kt = 0; kt < 4; ++kt) {
                UW u; u.q = Ar[kt * 4 + lk];
                xf[mt][kt] = u.v;
            }
        } else {
            const float* Ar = (const float*)Aptr + (size_t)mc * 128;
            #pragma unroll
            for (int kt = 0; kt < 4; ++kt) {
                int cb = kt * 32 + lk * 8;
                float4 p = *(const float4*)(Ar + cb);
                float4 q = *(const float4*)(Ar + cb + 4);
                UA u;
                u.u[0] = pack_f16(p.x, p.y);
                u.u[1] = pack_f16(p.z, p.w);
                u.u[2] = pack_f16(q.x, q.y);
                u.u[3] = pack_f16(q.z, q.w);
                xf[mt][kt] = u.v;
            }
        }
    }

    f32x4 acc[2][NT];
    #pragma unroll
    for (int mt = 0; mt < 2; ++mt)
        #pragma unroll
        for (int nt = 0; nt < NT; ++nt)
            #pragma unroll
            for (int r = 0; r < 4; ++r) acc[mt][nt][r] = 0.f;

    const uint4* wpv = (const uint4*)wp;
    #pragma unroll
    for (int kt = 0; kt < 4; ++kt) {
        f16x8 wf[NT];
        #pragma unroll
        for (int nt = 0; nt < NT; ++nt) {
            UW u; u.q = wpv[(kt * NT + nt) * 64 + lane];
            wf[nt] = u.v;
        }
        #pragma unroll
        for (int mt = 0; mt < 2; ++mt)
            #pragma unroll
            for (int nt = 0; nt < NT; ++nt)
                acc[mt][nt] = __builtin_amdgcn_mfma_f32_16x16x32_f16(
                    wf[nt], xf[mt][kt], acc[mt][nt], 0, 0, 0);
    }

    #pragma unroll
    for (int mt = 0; mt < 2; ++mt) {
        int m = mrow[mt];
        if (m < M) {
            float dd = dis[m];
            unsigned* gr = G + (size_t)m * ND;
            #pragma unroll
            for (int nt = 0; nt < NT; ++nt) {
                uint2 w;
                w.x = pack_f16(acc[mt][nt][0] * dd, acc[mt][nt][1] * dd);
                w.y = pack_f16(acc[mt][nt][2] * dd, acc[mt][nt][3] * dd);
                *(uint2*)(gr + nt * 8 + lk * 2) = w;
            }
        }
    }
}

// ---------------- aggregation layer 1: wave per dst, 16-deep, pk_f16 accumulate ----------------
__global__ __launch_bounds__(256) void k_agg1(
    const unsigned* __restrict__ g1, const int2* __restrict__ seg,
    const int* __restrict__ csr, const float* __restrict__ dis,
    const float* __restrict__ b1, unsigned* __restrict__ y1, int n)
{
    int wid  = (blockIdx.x * 256 + threadIdx.x) >> 6;
    int lane = threadIdx.x & 63;
    if (wid >= n) return;
    int d = wid;
    int2 se = seg[d];
    int beg = se.x, end = se.y;

    f16x2 a0 = {0, 0}, a1 = {0, 0}, a2 = {0, 0}, a3 = {0, 0};
    a0 += h2(g1[(size_t)d * 64 + lane]);   // self term
    int j = beg;
    for (; j + 16 <= end; j += 16) {
        unsigned v[16];
        #pragma unroll
        for (int k = 0; k < 16; ++k)
            v[k] = g1[(size_t)csr[j + k] * 64 + lane];
        #pragma unroll
        for (int k = 0; k < 16; k += 4) {
            a0 += h2(v[k]); a1 += h2(v[k + 1]); a2 += h2(v[k + 2]); a3 += h2(v[k + 3]);
        }
    }
    for (; j + 4 <= end; j += 4) {
        a0 += h2(g1[(size_t)csr[j    ] * 64 + lane]);
        a1 += h2(g1[(size_t)csr[j + 1] * 64 + lane]);
        a2 += h2(g1[(size_t)csr[j + 2] * 64 + lane]);
        a3 += h2(g1[(size_t)csr[j + 3] * 64 + lane]);
    }
    for (; j < end; ++j)
        a0 += h2(g1[(size_t)csr[j] * 64 + lane]);

    f16x2 m = (a0 + a1) + (a2 + a3);
    float ax = (float)m[0], ay = (float)m[1];

    float dd = dis[d];
    float2 bb = ((const float2*)b1)[lane];
    float ox = fmaxf(fmaf(dd, ax, bb.x), 0.f);
    float oy = fmaxf(fmaf(dd, ay, bb.y), 0.f);
    y1[(size_t)d * 64 + lane] = pack_f16(ox, oy);
}

// ---------------- aggregation layer 2 + L2 normalize: quarter-wave per edge, pk_f16 ----------------
__global__ __launch_bounds__(256) void k_agg2(
    const unsigned* __restrict__ g2, const int2* __restrict__ seg,
    const int* __restrict__ csr, const float* __restrict__ dis,
    const float* __restrict__ b2, float* __restrict__ out, int n)
{
    int wid  = (blockIdx.x * 256 + threadIdx.x) >> 6;
    int lane = threadIdx.x & 63;
    if (wid >= n) return;
    int d  = wid;
    int ql = lane & 15;
    int qh = lane >> 4;
    int2 se = seg[d];
    int beg = se.x, end = se.y;

    f16x2 cx0 = {0, 0}, cx1 = {0, 0}, cy0 = {0, 0}, cy1 = {0, 0};
    int j = beg;
    for (; j + 16 <= end; j += 16) {
        int s0 = csr[j      + qh];
        int s1 = csr[j + 4  + qh];
        int s2 = csr[j + 8  + qh];
        int s3 = csr[j + 12 + qh];
        uint2 v0 = *((const uint2*)(g2 + (size_t)s0 * 32) + ql);
        uint2 v1 = *((const uint2*)(g2 + (size_t)s1 * 32) + ql);
        uint2 v2 = *((const uint2*)(g2 + (size_t)s2 * 32) + ql);
        uint2 v3 = *((const uint2*)(g2 + (size_t)s3 * 32) + ql);
        cx0 += h2(v0.x); cy0 += h2(v0.y);
        cx1 += h2(v1.x); cy1 += h2(v1.y);
        cx0 += h2(v2.x); cy0 += h2(v2.y);
        cx1 += h2(v3.x); cy1 += h2(v3.y);
    }
    for (; j < end; j += 4) {
        if (j + qh < end) {
            int s = csr[j + qh];
            uint2 v = *((const uint2*)(g2 + (size_t)s * 32) + ql);
            cx0 += h2(v.x); cy0 += h2(v.y);
        }
    }
    f16x2 mx = cx0 + cx1;
    f16x2 my = cy0 + cy1;
    float a0 = (float)mx[0], a1 = (float)mx[1];
    float a2 = (float)my[0], a3 = (float)my[1];

    a0 += __shfl_xor(a0, 16, 64); a0 += __shfl_xor(a0, 32, 64);
    a1 += __shfl_xor(a1, 16, 64); a1 += __shfl_xor(a1, 32, 64);
    a2 += __shfl_xor(a2, 16, 64); a2 += __shfl_xor(a2, 32, 64);
    a3 += __shfl_xor(a3, 16, 64); a3 += __shfl_xor(a3, 32, 64);

    // self term (fp32 path)
    uint2 sv = *((const uint2*)(g2 + (size_t)d * 32) + ql);
    f16x2 sx = h2(sv.x), sy = h2(sv.y);
    a0 += (float)sx[0]; a1 += (float)sx[1];
    a2 += (float)sy[0]; a3 += (float)sy[1];

    float dd = dis[d];
    float4 bb = *(const float4*)(b2 + 4 * ql);
    float v0 = fmaf(dd, a0, bb.x);
    float v1 = fmaf(dd, a1, bb.y);
    float v2 = fmaf(dd, a2, bb.z);
    float v3 = fmaf(dd, a3, bb.w);

    float ss = v0 * v0 + v1 * v1 + v2 * v2 + v3 * v3;
    #pragma unroll
    for (int o = 8; o >= 1; o >>= 1)
        ss += __shfl_xor(ss, o, 64);
    float inv = 1.0f / fmaxf(sqrtf(ss), 1e-12f);
    if (lane < 16) {
        float4 w = make_float4(v0 * inv, v1 * inv, v2 * inv, v3 * inv);
        *((float4*)(out + (size_t)d * 64) + ql) = w;
    }
}

// ---------------- launcher ----------------
extern "C" void kernel_launch(void* const* d_in, const int* in_sizes, int n_in,
                              void* d_out, int out_size, void* d_ws, size_t ws_size,
                              hipStream_t stream) {
    const float* x  = (const float*)d_in[0];
    const int*   ei = (const int*)d_in[1];
    const float* W1 = (const float*)d_in[2];
    const float* b1 = (const float*)d_in[3];
    const float* W2 = (const float*)d_in[4];
    const float* b2 = (const float*)d_in[5];

    const int N = in_sizes[0] / 128;   // 100000
    const int E = in_sizes[1] / 2;     // 1600000
    const int* src = ei;
    const int* dst = ei + E;
    const int NC = (N + 511) >> CSHIFT;          // 196 coarse buckets
    const int PB = (E + TILE - 1) / TILE;        // 391 partition blocks

    char* ws = (char*)d_ws;
    size_t cur = 0;
    auto alloc = [&](size_t bytes) -> void* {
        void* p = ws + cur;
        cur += (bytes + 255) & ~(size_t)255;
        return p;
    };
    int2*           seg     = (int2*)           alloc((size_t)N * 8);
    int*            ccursor = (int*)            alloc((size_t)NC * 4);
    float*          dis     = (float*)          alloc((size_t)N * 4);
    int*            csr     = (int*)            alloc(((size_t)NC << PSH) * 4);  // padded CSR
    unsigned short* wp1     = (unsigned short*) alloc(16384 * 2);
    unsigned short* wp2     = (unsigned short*) alloc(8192 * 2);
    unsigned*       g1      = (unsigned*)       alloc((size_t)N * 64 * 4);  // fp16x2
    unsigned*       y1      = (unsigned*)       alloc((size_t)N * 64 * 4);  // fp16x2
    int*            pairs   = (int*)y1;          // padded bucket regions (12.9 MB), dead before y1
    unsigned*       g2      = g1;                // g1 dead after agg1; 32 dwords/row
    float*          out     = (float*)d_out;

    k_prep<<<96, 256, 0, stream>>>(W1, W2, wp1, wp2, ccursor, NC);
    k_part<<<PB, 256, 0, stream>>>(src, dst, E, ccursor, pairs, NC);
    k_build<<<NC, 256, 0, stream>>>(ccursor, pairs, seg, dis, csr, N);

    // layer 1: g1 = fp16((x @ W1) * dis)   [MFMA f16]
    k_gemm_mfma<128, false><<<(N + 127) / 128, 256, 0, stream>>>(x, wp1, dis, g1, N);
    k_agg1<<<(N * 64 + 255) / 256, 256, 0, stream>>>(g1, seg, csr, dis, b1, y1, N);

    // layer 2: g2 = fp16((y1 @ W2) * dis)  [MFMA f16]
    k_gemm_mfma<64, true><<<(N + 127) / 128, 256, 0, stream>>>(y1, wp2, dis, g2, N);
    k_agg2<<<(N * 64 + 255) / 256, 256, 0, stream>>>(g2, seg, csr, dis, b2, out, N);
}